// Round 16
// baseline (915.063 us; speedup 1.0000x reference)
//
#include <hip/hip_runtime.h>
#include <hip/hip_bf16.h>
#include <math.h>
#include <type_traits>

#define Bb 8
#define Cc 180
#define HWn 9216
#define PD 16
#define CRr 60
#define HID 360
#define H2 720
#define NF 49
#define SPL 9408   /* spectral plane stride in floats: 96*49*2 */
#define CONV_SCALE 0.01f
#define FFT_RES 0.15f
#define EPSLN 1e-5f
#define TWOPI_96 0.06544984694978735f

typedef __hip_bfloat16 bf16;
typedef unsigned short ushort;
typedef __attribute__((ext_vector_type(8))) short s8v;   // 8 bf16 (4 VGPRs) MFMA A/B frag
typedef __attribute__((ext_vector_type(4))) float f4v;   // MFMA C/D frag
struct us4 { ushort x,y,z,w; };

__device__ __forceinline__ float geluf(float x){ return 0.5f*x*(1.0f+erff(x*0.7071067811865476f)); }
__device__ __forceinline__ float sigm(float x){ return 1.0f/(1.0f+expf(-x)); }
__device__ __forceinline__ short f2bf(float f){
  unsigned u = __float_as_uint(f);
  u += 0x7fff + ((u>>16)&1);
  return (short)(u>>16);
}
__device__ __forceinline__ float bf2f(ushort u){ return __uint_as_float(((unsigned)u)<<16); }
__device__ __forceinline__ float wredsum(float v){
#pragma unroll
  for(int m=1;m<64;m<<=1) v += __shfl_xor(v,m,64);
  return v;
}

// ---------------- LN1 + transpose to (B,C,H,W) + fused plane-mean partials ----------------
__global__ void __launch_bounds__(256) k_ln1(const float* __restrict__ x, const float* __restrict__ g,
                      const float* __restrict__ be, float* __restrict__ ximg, float* __restrict__ m1){
  __shared__ float sb[32*Cc];
  int b = blockIdx.x / 288;
  int n0 = (blockIdx.x % 288) * 32;
  int t = threadIdx.x;
  const float* src = x + (size_t)(b*HWn + n0)*Cc;
  for(int i=t;i<32*Cc;i+=256) sb[i]=src[i];
  __syncthreads();
  int w = t>>6, lane = t&63;
  for(int pi=0; pi<8; ++pi){
    int p = w*8+pi;
    float s=0.f, sq=0.f;
    for(int e=lane;e<Cc;e+=64){ float v=sb[p*Cc+e]; s+=v; sq+=v*v; }
    s = wredsum(s); sq = wredsum(sq);
    float mean = s*(1.0f/180.0f);
    float var = sq*(1.0f/180.0f) - mean*mean;
    float rstd = rsqrtf(var + EPSLN);
    for(int e=lane;e<Cc;e+=64){ float v=sb[p*Cc+e]; sb[p*Cc+e] = (v-mean)*rstd*g[e]+be[e]; }
  }
  __syncthreads();
  if(t<Cc){
    float s=0.f;
#pragma unroll 8
    for(int p=0;p<32;p++) s += sb[p*Cc+t];
    atomicAdd(&m1[b*Cc+t], s*(1.0f/9216.0f));
  }
  for(int i=t;i<32*Cc;i+=256){
    int c = i/32, p = i%32;
    ximg[(size_t)(b*Cc+c)*HWn + n0 + p] = sb[p*Cc+c];
  }
}

// ---------------- small: gates, hdn->dk, fft bias ----------------
__global__ void k_small(const float* __restrict__ m1, const float* __restrict__ gate_w,
   const float* __restrict__ gate_b, const float* __restrict__ dwc_w1, const float* __restrict__ dwc_b1,
   const float* __restrict__ dwc_w2, const float* __restrict__ dwc_b2, const float* __restrict__ band_b,
   float* __restrict__ gates, float* __restrict__ dkb, float* __restrict__ biasb){
  int b = threadIdx.x;
  if(b>=Bb) return;
  const float* m = m1 + b*Cc;
  float gv[3];
  for(int k=0;k<3;k++){ float a=gate_b[k]; for(int c=0;c<Cc;c++) a+=m[c]*gate_w[k*Cc+c]; gv[k]=sigm(a);}
  float e0=expf(gv[0]), e1=expf(gv[1]), e2=expf(gv[2]); float inv=1.0f/(e0+e1+e2);
  float g0=e0*inv,g1=e1*inv,g2=e2*inv;
  gates[b*3+0]=g0; gates[b*3+1]=g1; gates[b*3+2]=g2;
  float hd[8];
  for(int j=0;j<8;j++){ float a=dwc_b1[j]; for(int c=0;c<PD;c++) a+=m[c]*dwc_w1[j*PD+c]; hd[j]=geluf(a);}
  for(int i=0;i<144;i++){ float a=dwc_b2[i]; for(int j=0;j<8;j++) a+=hd[j]*dwc_w2[i*8+j]; dkb[b*144+i]=a; }
  for(int d=0;d<Cc;d++) biasb[b*Cc+d] = g0*band_b[0*Cc+d]+g1*band_b[1*Cc+d]+g2*band_b[2*Cc+d];
}

// ------- pack weights to bf16 + DFT twiddle matrices (+ zero m1/gapb accumulators) -------
// Wbk, Wpa, Wp2 are packed FRAGMENT-MAJOR so each MFMA B-fragment load is lane-contiguous.
__global__ void __launch_bounds__(256) k_packw(const float* __restrict__ w1, const float* __restrict__ w2,
    const float* __restrict__ fw1, const float* __restrict__ fw2, const float* __restrict__ aw,
    const float* __restrict__ bw,
    ushort* __restrict__ Wg1, ushort* __restrict__ Wg2, ushort* __restrict__ Wp1,
    ushort* __restrict__ Wp2, ushort* __restrict__ Wpa, ushort* __restrict__ Wbk,
    ushort* __restrict__ Bfx, ushort* __restrict__ Tm, ushort* __restrict__ Bix,
    float* __restrict__ m1z, float* __restrict__ gapz){
  int t = blockIdx.x*256 + threadIdx.x;
  if(t < Bb*Cc){ m1z[t]=0.f; gapz[t]=0.f; }
  if(t < 64*9*192){
    int co = t/(9*192); int rem = t%(9*192); int tap = rem/192; int ci = rem%192;
    float v = (co<CRr && ci<Cc) ? w1[((size_t)(co*Cc+ci))*9 + tap] : 0.f;
    Wg1[t] = (ushort)f2bf(v);
  }
  if(t < 192*9*64){
    int co = t/(9*64); int rem = t%(9*64); int tap = rem/64; int ci = rem%64;
    float v = (co<Cc && ci<CRr) ? w2[((size_t)(co*CRr+ci))*9 + tap] : 0.f;
    Wg2[t] = (ushort)f2bf(v);
  }
  if(t < 768*192){
    int j=t/192, k=t%192;
    Wp1[t] = (ushort)f2bf((j<H2 && k<Cc)? fw1[(size_t)j*Cc+k] : 0.f);
  }
  // Wp2 fragment-major: t = (ct*12+k6)*512 + lane*8 + q ; d=ct*16+lr, c=kq*8+k6*32+q
  if(t < 192*384){
    int q = t&7; int rest = t>>3;
    int lane = rest&63; rest >>= 6;      // rest = frag = ct*12+k6
    int kq = lane>>4, lr = lane&15;
    int k6 = rest%12; int ct = rest/12;
    int d = ct*16+lr, c = kq*8 + k6*32 + q;
    Wp2[t] = (ushort)f2bf((d<Cc && c<HID)? fw2[(size_t)d*HID+c] : 0.f);
  }
  // Wpa fragment-major: t = ((jt*6+k6)*4+kq)*128 + lr*8 + q ; d=jt*16+lr, c=kq*8+k6*32+q
  if(t < 192*192){
    int q = t&7; int rest = t>>3;
    int lr = rest&15; rest >>= 4;
    int kq = rest&3; rest >>= 2;
    int k6 = rest%6; int jt = rest/6;
    int d = jt*16+lr, c = kq*8 + k6*32 + q;
    Wpa[t] = (ushort)f2bf((d<Cc && c<Cc)? aw[(size_t)d*Cc+c] : 0.f);
  }
  // Wbk fragment-major: t = (((k*12+ts)*6+k6)*4+kq)*128 + lr*8 + q ; d=ts*16+lr, c=kq*8+k6*32+q
  if(t < 3*192*192){
    int q = t&7; int rest = t>>3;
    int lr = rest&15; rest >>= 4;
    int kq = rest&3; rest >>= 2;
    int k6 = rest%6; rest /= 6;
    int ts = rest%12; int k = rest/12;
    int d = ts*16+lr, c = kq*8 + k6*32 + q;
    Wbk[t] = (ushort)f2bf((d<Cc && c<Cc)? bw[((size_t)k*Cc + d)*Cc + c] : 0.f);
  }
  if(t < 112*96){
    int n=t/96, k=t%96;
    float v=0.f;
    if(n<98){
      int kx=n>>1; int m=(k*kx)%96; float th=(float)m*TWOPI_96;
      v = ((n&1)? -sinf(th) : cosf(th)) * (1.0f/96.0f);
    }
    Bfx[t] = (ushort)f2bf(v);
  }
  if(t < 96*192){
    int r=t/192, k=t%192;
    int c=k>>1; int m=(r*c)%96; float th=(float)m*TWOPI_96;
    float v = (k&1)? sinf(th) : cosf(th);
    Tm[t] = (ushort)f2bf(v);
  }
  if(t < 96*128){
    int n=t/128, k=t%128;
    float v=0.f;
    if(k<98){
      int kx=k>>1; float wgt=(kx==0||kx==48)?1.0f:2.0f;
      int m=(n*kx)%96; float th=(float)m*TWOPI_96;
      v = ((k&1)? -wgt*sinf(th) : wgt*cosf(th)) * (1.0f/96.0f);
    }
    Bix[t] = (ushort)f2bf(v);
  }
}

// ------- pack plk + per-batch dynamic depthwise into Wdk[b][co][13ky][7kxp][2tl*16ci] bf16 -------
__global__ void __launch_bounds__(256) k_packplk(const float* __restrict__ plk,
    const float* __restrict__ dkb, ushort* __restrict__ Wdk){
  int t = blockIdx.x*256 + threadIdx.x;
  if(t >= Bb*PD*13*7*32) return;
  int k = t & 31; int rest = t >> 5;
  int kxp = rest % 7; rest /= 7;
  int ky = rest % 13; rest /= 13;
  int co = rest % PD; int b = rest / PD;
  int tl = k >> 4, ci = k & 15;
  int kx = kxp*2 + tl;
  float v = 0.f;
  if(kx < 13){
    v = plk[((size_t)(co*PD+ci)*13 + ky)*13 + kx];
    if(ci==co && ky>=5 && ky<8 && kx>=5 && kx<8)
      v += dkb[b*144 + co*9 + (ky-5)*3 + (kx-5)];
  }
  Wdk[t] = (ushort)f2bf(v);
}

// ---------------- fused forward 2D rDFT (per plane), MFMA, 8 waves ----------------
__global__ void __launch_bounds__(512) k_fft_fwd(const float* __restrict__ ximg,
    const ushort* __restrict__ Bfx, const ushort* __restrict__ Tm, float* __restrict__ S){
  __shared__ __align__(16) short Asi[96*104];
  __shared__ __align__(16) short Bv[112*200];
  int bc = blockIdx.x; int t = threadIdx.x;
  int w=t>>6, lane=t&63, kq=lane>>4, lr=lane&15;
  const float* src = ximg + (size_t)bc*HWn;
  for(int i=t;i<1152;i+=512){
    int y=i/12, seg=i%12;
    float4 v0 = *(const float4*)(src + y*96 + seg*8);
    float4 v1 = *(const float4*)(src + y*96 + seg*8 + 4);
    s8v pk;
    pk[0]=f2bf(v0.x); pk[1]=f2bf(v0.y); pk[2]=f2bf(v0.z); pk[3]=f2bf(v0.w);
    pk[4]=f2bf(v1.x); pk[5]=f2bf(v1.y); pk[6]=f2bf(v1.z); pk[7]=f2bf(v1.w);
    *(s8v*)&Asi[y*104+seg*8] = pk;
  }
  __syncthreads();
  for(int tile=w; tile<42; tile+=8){
    int mt=tile/7, nt=tile%7;
    f4v acc={};
#pragma unroll
    for(int ks=0;ks<3;ks++){
      s8v af = *(const s8v*)&Asi[(mt*16+lr)*104 + kq*8 + ks*32];
      s8v bf = *(const s8v*)&Bfx[(size_t)(nt*16+lr)*96 + kq*8 + ks*32];
      acc = __builtin_amdgcn_mfma_f32_16x16x32_bf16(af,bf,acc,0,0,0);
    }
    int n = nt*16+lr;
    float sgn = (n&1)? -1.f : 1.f;
#pragma unroll
    for(int reg=0;reg<4;reg++){
      int y = mt*16+kq*4+reg;
      float v = acc[reg];
      float p = __shfl_xor(v,1);
      unsigned pack = ((unsigned)(ushort)f2bf(sgn*p)<<16) | (ushort)(unsigned short)f2bf(v);
      *(unsigned*)&Bv[n*200 + 2*y] = pack;
    }
  }
  __syncthreads();
  float* dst = S + (size_t)bc*SPL;
  for(int tile=w; tile<42; tile+=8){
    int mt=tile/7, nt=tile%7;
    f4v acc={};
#pragma unroll
    for(int ks=0;ks<6;ks++){
      s8v af = *(const s8v*)&Tm[(size_t)(mt*16+lr)*192 + kq*8 + ks*32];
      s8v bf = *(const s8v*)&Bv[(nt*16+lr)*200 + kq*8 + ks*32];
      acc = __builtin_amdgcn_mfma_f32_16x16x32_bf16(af,bf,acc,0,0,0);
    }
    int n = nt*16+lr;
    if(n<98){
#pragma unroll
      for(int reg=0;reg<4;reg++){
        int ky = mt*16+kq*4+reg;
        dst[ky*98 + n] = acc[reg];
      }
    }
  }
}

// ---------------- fused inverse 2D rDFT + combine (per plane), MFMA, 8 waves ----------------
__global__ void __launch_bounds__(512) k_fft_inv(float* __restrict__ S, const float* __restrict__ ximg,
    const float* __restrict__ biasb, const ushort* __restrict__ Tm, const ushort* __restrict__ Bix){
  __shared__ __align__(16) short Bv[112*200];
  __shared__ __align__(16) short T2s[96*136];
  int bd = blockIdx.x; int t=threadIdx.x;
  int w=t>>6, lane=t&63, kq=lane>>4, lr=lane&15;
  int b = bd/Cc, d = bd%Cc;
  float* pl = S + (size_t)bd*SPL;
  for(int i=t;i<1400;i+=512) ((unsigned*)&Bv[98*200])[i] = 0u;
  for(int i=t;i<1152;i+=512){ int y=i/12, c=i%12; *(unsigned*)&T2s[y*136+112+c*2] = 0u; }
  for(int i2=t;i2<4704;i2+=512){
    int idx = i2*2;
    float2 v = *(const float2*)(pl + idx);
    int ky = idx/98, n = idx%98;     // n even
    unsigned pack0 = ((unsigned)(ushort)f2bf(-v.y)<<16) | (ushort)(unsigned short)f2bf(v.x);
    unsigned pack1 = ((unsigned)(ushort)f2bf( v.x)<<16) | (ushort)(unsigned short)f2bf(v.y);
    *(unsigned*)&Bv[n*200 + 2*ky]     = pack0;
    *(unsigned*)&Bv[(n+1)*200 + 2*ky] = pack1;
  }
  __syncthreads();
  for(int tile=w; tile<42; tile+=8){
    int mt=tile/7, nt=tile%7;
    f4v acc={};
#pragma unroll
    for(int ks=0;ks<6;ks++){
      s8v af = *(const s8v*)&Tm[(size_t)(mt*16+lr)*192 + kq*8 + ks*32];
      s8v bf = *(const s8v*)&Bv[(nt*16+lr)*200 + kq*8 + ks*32];
      acc = __builtin_amdgcn_mfma_f32_16x16x32_bf16(af,bf,acc,0,0,0);
    }
    int n = nt*16+lr;
#pragma unroll
    for(int reg=0;reg<4;reg++){
      int y = mt*16+kq*4+reg;
      T2s[y*136 + n] = f2bf(acc[reg]);
    }
  }
  __syncthreads();
  float bias = biasb[b*Cc+d];
  const float* xs = ximg + (size_t)bd*HWn;
  ushort* po = (ushort*)pl;
  for(int tile=w; tile<36; tile+=8){
    int mt=tile/6, nt=tile%6;
    f4v acc={};
#pragma unroll
    for(int ks=0;ks<4;ks++){
      s8v af = *(const s8v*)&T2s[(mt*16+lr)*136 + kq*8 + ks*32];
      s8v bf = *(const s8v*)&Bix[(size_t)(nt*16+lr)*128 + kq*8 + ks*32];
      acc = __builtin_amdgcn_mfma_f32_16x16x32_bf16(af,bf,acc,0,0,0);
    }
    int xx = nt*16+lr;
#pragma unroll
    for(int reg=0;reg<4;reg++){
      int y = mt*16+kq*4+reg;
      int o = y*96+xx;
      po[o] = (ushort)f2bf(xs[o] + FFT_RES*(acc[reg] + bias));
    }
  }
}

// ---------------- band channel mix as MFMA GEMM, IN-PLACE, 8 waves, Wbk fragment-major ----------------
__global__ void __launch_bounds__(512) k_bandmixm(float* __restrict__ S, const ushort* __restrict__ Wbk,
                          const float* __restrict__ gates){
  __shared__ __align__(16) short Bs[64*200];
  int f2base = blockIdx.x*64;
  int b = blockIdx.y;
  int t = threadIdx.x;
  int w=t>>6, lane=t&63, kq=lane>>4, lr=lane&15;
  int wr = w&3, chh = w>>2;
  for(int i=t;i<8*192;i+=512){
    int rblk=i&7, kk=i>>3;
    int r0=rblk*8;
    if(kk<Cc){
      const float* src = S + (size_t)(b*Cc+kk)*SPL + f2base + r0;
      float4 v0 = *(const float4*)src;
      float4 v1 = *(const float4*)(src+4);
      Bs[(r0+0)*200+kk]=f2bf(v0.x); Bs[(r0+1)*200+kk]=f2bf(v0.y);
      Bs[(r0+2)*200+kk]=f2bf(v0.z); Bs[(r0+3)*200+kk]=f2bf(v0.w);
      Bs[(r0+4)*200+kk]=f2bf(v1.x); Bs[(r0+5)*200+kk]=f2bf(v1.y);
      Bs[(r0+6)*200+kk]=f2bf(v1.z); Bs[(r0+7)*200+kk]=f2bf(v1.w);
    } else {
#pragma unroll
      for(int q=0;q<8;q++) Bs[(r0+q)*200+kk]=0;
    }
  }
  unsigned bmask;
  {
    int col = f2base + lane;
    int ky = col/98, n = col%98, kx = n>>1;
    float yy = -1.0f + 2.0f*(float)ky/95.0f;
    float xxf = (float)kx/48.0f;
    float rr = sqrtf(yy*yy+xxf*xxf);
    int k = (rr<=0.25f)?0:((rr<=0.6f)?1:2);
    unsigned m = 1u<<k;
#pragma unroll
    for(int s=1;s<64;s<<=1) m |= __shfl_xor(m,s);
    bmask = m;
  }
  int kb[4]; float gv[4];
#pragma unroll
  for(int reg=0;reg<4;reg++){
    int col = f2base + wr*16 + kq*4 + reg;
    int ky = col/98, n = col%98, kx = n>>1;
    float yy = -1.0f + 2.0f*(float)ky/95.0f;
    float xxf = (float)kx/48.0f;
    float rr = sqrtf(yy*yy+xxf*xxf);
    kb[reg] = (rr<=0.25f)?0:((rr<=0.6f)?1:2);
    gv[reg] = gates[b*3+kb[reg]];
  }
  __syncthreads();
  s8v af[6];
#pragma unroll
  for(int k6=0;k6<6;k6++) af[k6] = *(const s8v*)&Bs[(wr*16+lr)*200 + kq*8 + k6*32];
  float res[6][4];
  for(int k=0;k<3;k++){
    if(!(bmask&(1u<<k))) continue;
    for(int j=0;j<6;j++){
      int ts = chh*6 + j;
      f4v acc={};
#pragma unroll
      for(int k6=0;k6<6;k6++){
        s8v wf = *(const s8v*)&Wbk[((size_t)((k*12+ts)*6 + k6))*512 + lane*8];
        acc = __builtin_amdgcn_mfma_f32_16x16x32_bf16(af[k6],wf,acc,0,0,0);
      }
#pragma unroll
      for(int reg=0;reg<4;reg++) if(kb[reg]==k) res[j][reg]=gv[reg]*acc[reg];
    }
  }
#pragma unroll
  for(int j=0;j<6;j++){
    int d = (chh*6+j)*16+lr;
    if(d<Cc){
      float4 o; o.x=res[j][0]; o.y=res[j][1]; o.z=res[j][2]; o.w=res[j][3];
      *(float4*)(S + (size_t)(b*Cc+d)*SPL + f2base + wr*16 + kq*4) = o;
    }
  }
}

// ---------------- CAB 3x3 conv as implicit-GEMM MFMA, bf16 in/out, vectorized staging ----------------
template<int NW, int CIN, int KPAD, int NCHUNK, bool ACT, bool OUTBF>
__global__ void __launch_bounds__(NW*64) k_cab(const ushort* __restrict__ xin, const ushort* __restrict__ Wg,
    const float* __restrict__ bias, ushort* __restrict__ out, int COUT, int istride,
    float* __restrict__ gapp){
  constexpr int NT = NW*64;
  constexpr int STILES = 12/NW;
  __shared__ short As[4*98*36];
  int y0 = blockIdx.x*2;
  int ct = blockIdx.y;
  int b  = blockIdx.z;
  int t = threadIdx.x;
  int w = t>>6, lane = t&63, kq = lane>>4, lr = lane&15;
  f4v acc[STILES][4] = {};
  for(int ch=0; ch<NCHUNK; ++ch){
    int ci0 = ch*32;
    __syncthreads();
    for(int u=t; u<4*12*32; u+=NT){
      int ci = u&31; int rest = u>>5; int seg = rest%12; int row = rest/12;
      int gy = y0 - 1 + row; int cig = ci0+ci;
      s8v v = {};
      if((unsigned)gy<96u && cig<CIN)
        v = *(const s8v*)&xin[(size_t)(b*CIN+cig)*istride + gy*96 + seg*8];
      int base = (row*98 + seg*8 + 1)*36 + ci;
#pragma unroll
      for(int q=0;q<8;q++) As[base + q*36] = v[q];
    }
    for(int u=t; u<4*2*32; u+=NT){
      int ci=u&31; int rest=u>>5; int e=rest&1; int row=rest>>1;
      As[(row*98 + (e?97:0))*36 + ci] = 0;
    }
    __syncthreads();
#pragma unroll
    for(int tap=0; tap<9; ++tap){
      int ky = tap/3, kx = tap%3;
      s8v bfr[4];
#pragma unroll
      for(int ts=0;ts<4;ts++)
        bfr[ts] = *(const s8v*)&Wg[((size_t)(ct*64 + ts*16 + lr)*9 + tap)*KPAD + ci0 + kq*8];
#pragma unroll
      for(int s=0;s<STILES;s++){
        int mt = w + NW*s;
        int orow = mt/6, px = (mt%6)*16 + lr;
        s8v af = *(const s8v*)&As[((orow+ky)*98 + px + kx)*36 + kq*8];
#pragma unroll
        for(int ts=0;ts<4;ts++)
          acc[s][ts] = __builtin_amdgcn_mfma_f32_16x16x32_bf16(af, bfr[ts], acc[s][ts], 0,0,0);
      }
    }
  }
  if(OUTBF){
    __syncthreads();
    short* cT = As;
#pragma unroll
    for(int ts=0;ts<4;ts++){
      int cog = ct*64 + ts*16 + lr;
      float bb = (cog<COUT)? bias[cog] : 0.f;
#pragma unroll
      for(int s=0;s<STILES;s++){
        int mt = w + NW*s;
#pragma unroll
        for(int reg=0;reg<4;reg++){
          int px = mt*16 + kq*4 + reg;
          float v = acc[s][ts][reg] + bb;
          if(ACT) v = geluf(v);
          cT[(ts*16+lr)*200 + px] = f2bf(v);
        }
      }
    }
    __syncthreads();
    for(int i=t;i<64*24;i+=NT){
      int co=i/24, seg=i%24;
      int cog = ct*64+co;
      if(cog<COUT)
        *(s8v*)&out[(size_t)(b*COUT+cog)*HWn + y0*96 + seg*8] = *(const s8v*)&cT[co*200+seg*8];
    }
  } else {
    float* cF = (float*)As;
    for(int h=0;h<2;h++){
      __syncthreads();
#pragma unroll
      for(int tt=0;tt<2;tt++){
        int ts = 2*h+tt;
        int cog = ct*64 + ts*16 + lr;
        float bb = (cog<COUT)? bias[cog] : 0.f;
#pragma unroll
        for(int s=0;s<STILES;s++){
          int mt = w + NW*s;
#pragma unroll
          for(int reg=0;reg<4;reg++){
            int px = mt*16 + kq*4 + reg;
            cF[(tt*16+lr)*200 + px] = acc[s][ts][reg] + bb;
          }
        }
      }
      __syncthreads();
      for(int i=t;i<32*24;i+=NT){
        int co=i/24, seg=i%24;
        int cog = ct*64 + h*32 + co;
        if(cog<COUT){
          s8v pk;
#pragma unroll
          for(int q=0;q<8;q++) pk[q] = f2bf(cF[co*200+seg*8+q]);
          *(s8v*)&out[(size_t)(b*COUT+cog)*HWn + y0*96 + seg*8] = pk;
        }
      }
      if(gapp){
        for(int row=w; row<32; row+=NW){
          int cog = ct*64 + h*32 + row;
          float s=0.f;
#pragma unroll
          for(int px=lane;px<192;px+=64) s += cF[row*200+px];
          s = wredsum(s);
          if(lane==0 && cog<COUT) atomicAdd(&gapp[(size_t)b*COUT+cog], s*(1.0f/9216.0f));
        }
      }
    }
  }
}

// ---------------- ECA ----------------
__global__ void k_eca(const float* __restrict__ gap, const float* __restrict__ ew, float* __restrict__ s){
  int i = blockIdx.x*blockDim.x + threadIdx.x;
  if(i>=Bb*Cc) return;
  int b=i/Cc, c=i%Cc;
  float z=0.f;
  for(int j=0;j<5;j++){ int cc=c-2+j; if(cc>=0&&cc<Cc) z+=gap[b*Cc+cc]*ew[j]; }
  s[i]=sigm(z);
}

// ------- plk 13x13 + fused dynamic dw3x3 as implicit-GEMM MFMA (tap-pair K=32), 6 waves -------
__global__ void __launch_bounds__(384) k_plkm(const float* __restrict__ ximg,
    const ushort* __restrict__ Wdk, float* __restrict__ attn){
  __shared__ short As[15*109*20];
  int y0 = blockIdx.x*3;
  int b  = blockIdx.y;
  int t = threadIdx.x;
  int w = t>>6, lane = t&63, kq = lane>>4, lr = lane&15;
  for(int i=t;i<PD*15*109;i+=384){
    int ci = i/(15*109); int rem = i%(15*109);
    int row = rem/109, pxh = rem%109;
    int gy = y0 + row - 6, gx = pxh - 6;
    short sv = 0;
    if((unsigned)gy<96u && (unsigned)gx<96u)
      sv = f2bf(ximg[(size_t)(b*Cc+ci)*HWn + gy*96 + gx]);
    As[(row*109+pxh)*20 + ci] = sv;
  }
  __syncthreads();
  f4v acc[3] = {};
  const ushort* wb = Wdk + ((size_t)(b*PD+lr)*13)*7*32 + kq*8;
  for(int ky=0;ky<13;ky++){
#pragma unroll
    for(int kxp=0;kxp<7;kxp++){
      s8v bfr = *(const s8v*)(wb + (ky*7+kxp)*32);
#pragma unroll
      for(int ti=0;ti<3;ti++){
        int mt = w + 6*ti;
        int yo = mt/6, o = (mt%6)*16;
        s8v af = *(const s8v*)&As[((yo+ky)*109 + o + lr + 2*kxp + (kq>>1))*20 + (kq&1)*8];
        acc[ti] = __builtin_amdgcn_mfma_f32_16x16x32_bf16(af, bfr, acc[ti], 0,0,0);
      }
    }
  }
#pragma unroll
  for(int ti=0;ti<3;ti++){
    int mt = w + 6*ti;
    int yo = mt/6, o = (mt%6)*16 + kq*4;
    float4 ov; ov.x=acc[ti][0]; ov.y=acc[ti][1]; ov.z=acc[ti][2]; ov.w=acc[ti][3];
    *(float4*)&attn[(size_t)(b*PD+lr)*HWn + (y0+yo)*96 + o] = ov;
  }
}

// ---------------- aggr MFMA GEMM, 8 waves, Wpa fragment-major; + residual + LN2 ----------------
__global__ void __launch_bounds__(512) k_aggrm(const float* __restrict__ x, const float* __restrict__ attn,
   const float* __restrict__ ximg, const ushort* __restrict__ ycab, const ushort* __restrict__ Wpa,
   const float* __restrict__ aggb, const float* __restrict__ svec,
   const float* __restrict__ g2, const float* __restrict__ b2,
   float* __restrict__ xm, ushort* __restrict__ xn2){
  __shared__ __align__(16) float smem[64*188];
  short* As = (short*)smem;
  float* cF = smem;
  int rt = blockIdx.x;
  int t = threadIdx.x;
  int w = t>>6, lane = t&63, kq = lane>>4, lr = lane&15;
  int grow0 = rt*64; int b = grow0/HWn; int n0 = grow0%HWn;
  for(int i=t;i<8*192;i+=512){
    int rblk=i&7, kk=i>>3;
    int r0=rblk*8;
    if(kk<Cc){
      const float* src = (kk<PD)? attn + (size_t)(b*PD+kk)*HWn + n0 + r0
                                : ximg + (size_t)(b*Cc+kk)*HWn + n0 + r0;
      float4 v0 = *(const float4*)src;
      float4 v1 = *(const float4*)(src+4);
      As[(r0+0)*200+kk]=f2bf(v0.x); As[(r0+1)*200+kk]=f2bf(v0.y);
      As[(r0+2)*200+kk]=f2bf(v0.z); As[(r0+3)*200+kk]=f2bf(v0.w);
      As[(r0+4)*200+kk]=f2bf(v1.x); As[(r0+5)*200+kk]=f2bf(v1.y);
      As[(r0+6)*200+kk]=f2bf(v1.z); As[(r0+7)*200+kk]=f2bf(v1.w);
    } else {
#pragma unroll
      for(int q=0;q<8;q++) As[(r0+q)*200+kk]=0;
    }
  }
  __syncthreads();
  int wr = w&3, ch = w>>2;
  s8v af[6];
  int arow=(wr*16+lr)*200 + kq*8;
#pragma unroll
  for(int k6=0;k6<6;k6++) af[k6] = *(const s8v*)&As[arow + k6*32];
  f4v acc[6]={};
#pragma unroll
  for(int j=0;j<6;j++){
    int jt = ch*6+j;
#pragma unroll
    for(int k6=0;k6<6;k6++){
      s8v wf = *(const s8v*)&Wpa[((size_t)(jt*6 + k6))*512 + lane*8];
      acc[j]=__builtin_amdgcn_mfma_f32_16x16x32_bf16(af[k6],wf,acc[j],0,0,0);
    }
  }
  __syncthreads();
#pragma unroll
  for(int j=0;j<6;j++){
    int jc = (ch*6+j)*16 + lr;
    if(jc<Cc){
      float bb = aggb[jc];
      float sv = CONV_SCALE*svec[b*Cc+jc];
      const ushort* yrow = ycab + (size_t)(b*Cc+jc)*HWn + n0;
#pragma unroll
      for(int reg=0;reg<4;reg++){
        int m = wr*16 + kq*4 + reg;
        cF[m*188+jc] = acc[j][reg] + bb + sv*bf2f(yrow[m]);
      }
    }
  }
  __syncthreads();
  for(int r=0;r<8;r++){
    int m = w*8 + r;
    size_t baseo = (size_t)(grow0+m)*Cc;
    float vbuf[3];
    float s=0.f, sq=0.f;
#pragma unroll
    for(int it=0;it<3;it++){
      int e = lane + it*64;
      float v = (e<Cc)? cF[m*188+e] + x[baseo+e] : 0.f;
      vbuf[it]=v; s+=v; sq+=v*v;
    }
    s=wredsum(s); sq=wredsum(sq);
    float mean = s*(1.0f/180.0f);
    float var = sq*(1.0f/180.0f) - mean*mean;
    float rstd = rsqrtf(var + EPSLN);
    ushort* orow = xn2 + (size_t)(grow0+m)*192;
#pragma unroll
    for(int it=0;it<3;it++){
      int e = lane + it*64;
      if(e<Cc){
        float v = vbuf[it];
        xm[baseo+e] = v;
        orow[e] = (ushort)f2bf((v-mean)*rstd*g2[e]+b2[e]);
      } else {
        orow[e] = 0;
      }
    }
  }
}

// -------- fc1 MFMA: W-tile staged to LDS via coalesced s8v copies --------
__global__ void __launch_bounds__(256) k_fc1(const ushort* __restrict__ xn2,
    const ushort* __restrict__ Wp, const float* __restrict__ fb, ushort* __restrict__ t1){
  __shared__ __align__(16) short Ws[64*200];
  int rt = blockIdx.x;
  int t = threadIdx.x;
  int w = t>>6, lane = t&63, kq = lane>>4, lr = lane&15;
  int grow0 = rt*64;
  int bb_ = grow0/HWn, n0 = grow0%HWn;
  s8v af[6];
  const ushort* arow = xn2 + (size_t)(grow0 + w*16 + lr)*192 + kq*8;
#pragma unroll
  for(int k6=0;k6<6;k6++) af[k6] = *(const s8v*)(arow + k6*32);
  int mcol = n0 + w*16 + kq*4;
  for(int ct=0; ct<12; ++ct){
    __syncthreads();
    const s8v* src = (const s8v*)(Wp + (size_t)ct*64*192);
#pragma unroll
    for(int q=0;q<6;q++){
      int i = t + q*256;
      int j = i/24, seg = i%24;
      *(s8v*)&Ws[j*200 + seg*8] = src[i];
    }
    __syncthreads();
    f4v acc[4]={};
#pragma unroll
    for(int k6=0;k6<6;k6++){
#pragma unroll
      for(int ts=0;ts<4;ts++){
        s8v wf = *(const s8v*)&Ws[(ts*16+lr)*200 + kq*8 + k6*32];
        acc[ts]=__builtin_amdgcn_mfma_f32_16x16x32_bf16(af[k6],wf,acc[ts],0,0,0);
      }
    }
#pragma unroll
    for(int ts=0;ts<4;ts++){
      int jc = ct*64 + ts*16 + lr;
      if(jc<H2){
        float bb = fb[jc];
        us4 pk;
        pk.x=(ushort)f2bf(acc[ts][0]+bb); pk.y=(ushort)f2bf(acc[ts][1]+bb);
        pk.z=(ushort)f2bf(acc[ts][2]+bb); pk.w=(ushort)f2bf(acc[ts][3]+bb);
        *(us4*)&t1[((size_t)(bb_*H2+jc))*HWn + mcol] = pk;
      }
    }
  }
}

// ---------------- depthwise 3x3 on t1 + GLU -> pg (B,360,HW) bf16 ----------------
__global__ void __launch_bounds__(256) k_dwglu(const bf16* __restrict__ t1, const float* __restrict__ dww,
    const float* __restrict__ dwb, bf16* __restrict__ pg){
  __shared__ float ta[34*34];
  __shared__ float tg[34*34];
  int tile_id=blockIdx.x; int c=blockIdx.y; int b=blockIdx.z;
  int ty0=(tile_id/3)*32, tx0=(tile_id%3)*32;
  int t=threadIdx.x;
  int px0=(t%16)*2, py0=(t/16)*2;
  for(int i=t;i<34*34;i+=256){
    int ly=i/34, lx=i%34; int gy=ty0+ly-1, gx=tx0+lx-1;
    bool ok=((unsigned)gy<96u&&(unsigned)gx<96u);
    ta[i]= ok? __bfloat162float(t1[((size_t)(b*H2+c)*96+gy)*96+gx]) :0.f;
    tg[i]= ok? __bfloat162float(t1[((size_t)(b*H2+c+HID)*96+gy)*96+gx]) :0.f;
  }
  __syncthreads();
  float wp[9],wg[9];
#pragma unroll
  for(int i=0;i<9;i++){ wp[i]=dww[c*9+i]; wg[i]=dww[(c+HID)*9+i]; }
  float bp=dwb[c], bg=dwb[c+HID];
#pragma unroll
  for(int oy=0;oy<2;oy++)
#pragma unroll
    for(int ox=0;ox<2;ox++){
      float p=bp,g=bg;
#pragma unroll
      for(int ky=0;ky<3;ky++)
#pragma unroll
        for(int kx=0;kx<3;kx++){
          p+=wp[ky*3+kx]*ta[(py0+oy+ky)*34+px0+ox+kx];
          g+=wg[ky*3+kx]*tg[(py0+oy+ky)*34+px0+ox+kx];
        }
      float val = p * g * sigm(g);
      pg[((size_t)(b*HID+c)*96 + ty0+py0+oy)*96 + tx0+px0+ox] = __float2bfloat16(val);
    }
}

// ---------------- fc2 MFMA + residual -> out (B,N,C); BM=32, XOR-swizzled A staging,
//                  Wp2 FRAGMENT-MAJOR (lane-contiguous weight loads) ----------------
__global__ void __launch_bounds__(256) k_fc2(const ushort* __restrict__ pg, const float* __restrict__ xm,
    const ushort* __restrict__ Wp, const float* __restrict__ fb, float* __restrict__ out){
  __shared__ __align__(16) short As[32*392];
  float* cF = (float*)As;
  int rt = blockIdx.x;
  int t = threadIdx.x;
  int w = t>>6, lane = t&63, kq = lane>>4, lr = lane&15;
  int grow0 = rt*32; int b = grow0/HWn; int n0 = grow0%HWn;
  for(int i=t;i<4*HID;i+=256){
    int rblk = i&3; int kc = i>>2;
    int r0 = rblk*8;
    s8v v = *(const s8v*)&pg[((size_t)(b*HID+kc))*HWn + n0 + r0];
    int kcs = kc ^ (rblk<<3);
#pragma unroll
    for(int q=0;q<8;q++) As[(r0+q)*392 + kcs] = v[q];
  }
  for(int i=t;i<32*24;i+=256){
    int r = i/24, kc = 360 + i%24;
    As[r*392 + (kc ^ ((r>>3)<<3))] = 0;
  }
  __syncthreads();
  int mt = w&1;
  int row = mt*16 + lr;
  int rb = row>>3;
  s8v af[12];
#pragma unroll
  for(int k6=0;k6<12;k6++)
    af[k6] = *(const s8v*)&As[row*392 + ((kq ^ rb)<<3) + k6*32];
  f4v acc[6]={};
#pragma unroll
  for(int j=0;j<6;j++){
    int ct = (w>>1) + 2*j;
#pragma unroll
    for(int k6=0;k6<12;k6++){
      // fragment-major Wp2: lane-contiguous 16B loads
      s8v wf = *(const s8v*)&Wp[(size_t)(ct*12 + k6)*512 + lane*8];
      acc[j]=__builtin_amdgcn_mfma_f32_16x16x32_bf16(af[k6],wf,acc[j],0,0,0);
    }
  }
  __syncthreads();
#pragma unroll
  for(int j=0;j<6;j++){
    int ct = (w>>1) + 2*j;
    int jc = ct*16 + lr;
    if(jc<Cc){
      float bb = fb[jc];
#pragma unroll
      for(int reg=0;reg<4;reg++){
        int m = mt*16 + kq*4 + reg;
        cF[m*Cc + jc] = acc[j][reg] + bb;
      }
    }
  }
  __syncthreads();
  size_t base = (size_t)grow0*Cc;
  for(int i=t;i<32*Cc;i+=256){
    out[base+i] = xm[base+i] + cF[i];
  }
}

extern "C" void kernel_launch(void* const* d_in, const int* in_sizes, int n_in,
                              void* d_out, int out_size, void* d_ws, size_t ws_size,
                              hipStream_t stream){
  (void)in_sizes; (void)n_in; (void)out_size; (void)ws_size;
  const float* x     = (const float*)d_in[0];
  const float* ln1_g = (const float*)d_in[3];
  const float* ln1_b = (const float*)d_in[4];
  const float* band_w= (const float*)d_in[5];
  const float* band_b= (const float*)d_in[6];
  const float* gate_w= (const float*)d_in[7];
  const float* gate_b= (const float*)d_in[8];
  const float* cab_w1= (const float*)d_in[9];
  const float* cab_b1= (const float*)d_in[10];
  const float* cab_w2= (const float*)d_in[11];
  const float* cab_b2= (const float*)d_in[12];
  const float* eca_w = (const float*)d_in[13];
  const float* plkw  = (const float*)d_in[14];
  const float* dwc_w1= (const float*)d_in[15];
  const float* dwc_b1= (const float*)d_in[16];
  const float* dwc_w2= (const float*)d_in[17];
  const float* dwc_b2= (const float*)d_in[18];
  const float* aggr_w= (const float*)d_in[19];
  const float* aggr_b= (const float*)d_in[20];
  const float* ln2_g = (const float*)d_in[21];
  const float* ln2_b = (const float*)d_in[22];
  const float* fc1_w = (const float*)d_in[23];
  const float* fc1_b = (const float*)d_in[24];
  const float* dw_w  = (const float*)d_in[25];
  const float* dw_b  = (const float*)d_in[26];
  const float* fc2_w = (const float*)d_in[27];
  const float* fc2_b = (const float*)d_in[28];

  float* ws = (float*)d_ws;
  float* xm   = ws;                      // 13,271,040
  float* m1   = ws + 13271040;
  float* gates= ws + 13272480;
  float* dkb  = ws + 13272512;
  float* biasb= ws + 13273664;
  float* gapb = ws + 13275104;
  float* svec = ws + 13276544;
  ushort* Wg1 = (ushort*)(ws + 13278000);
  ushort* Wg2 = (ushort*)(ws + 13333296);
  ushort* Wp1 = (ushort*)(ws + 13388592);
  ushort* Wp2 = (ushort*)(ws + 13462320);
  ushort* Wpa = (ushort*)(ws + 13499184);
  ushort* Bfx = (ushort*)(ws + 13517616);
  ushort* Tmw = (ushort*)(ws + 13522992);
  ushort* Bix = (ushort*)(ws + 13532208);
  ushort* Wbk = (ushort*)(ws + 13538352);
  ushort* Wdk = (ushort*)(ws + 13593648);
  float* big  = ws + 13780096;
  float* ximg = big;
  float* spec = big + 13271040;
  ushort* mid = (ushort*)(big + 26818560);
  float* attn = big + 29030400;
  ushort* ycab = (ushort*)spec;
  ushort* xn2 = (ushort*)(big + 30210048);
  ushort* t1  = (ushort*)big;
  float*  reg2= big + 26542080;
  ushort* pgb = (ushort*)reg2;

  k_packw<<<576,256,0,stream>>>(cab_w1, cab_w2, fc1_w, fc2_w, aggr_w, band_w,
                                Wg1, Wg2, Wp1, Wp2, Wpa, Wbk, Bfx, Tmw, Bix, m1, gapb);
  k_ln1<<<2304,256,0,stream>>>(x, ln1_g, ln1_b, ximg, m1);
  k_small<<<1,64,0,stream>>>(m1, gate_w, gate_b, dwc_w1, dwc_b1, dwc_w2, dwc_b2, band_b, gates, dkb, biasb);
  k_packplk<<<1456,256,0,stream>>>(plkw, dkb, Wdk);
  k_fft_fwd<<<1440,512,0,stream>>>(ximg, Bfx, Tmw, spec);
  k_bandmixm<<<dim3(147,Bb),512,0,stream>>>(spec, Wbk, gates);
  k_fft_inv<<<1440,512,0,stream>>>(spec, ximg, biasb, Tmw, Bix);
  k_cab<4, Cc, 192, 6, true,  true ><<<dim3(48,1,Bb),256,0,stream>>>((const ushort*)spec, Wg1, cab_b1, mid, CRr, 2*SPL, nullptr);
  k_cab<4, CRr, 64, 2, false, false><<<dim3(48,3,Bb),256,0,stream>>>(mid, Wg2, cab_b2, ycab, Cc, HWn, gapb);
  k_eca<<<6,256,0,stream>>>(gapb, eca_w, svec);
  k_plkm<<<dim3(32,Bb),384,0,stream>>>(ximg, Wdk, attn);
  k_aggrm<<<1152,512,0,stream>>>(x, attn, ximg, ycab, Wpa, aggr_b, svec, ln2_g, ln2_b, xm, xn2);
  k_fc1<<<1152,256,0,stream>>>(xn2, Wp1, fc1_b, t1);
  k_dwglu<<<dim3(9,HID,Bb),256,0,stream>>>((const bf16*)t1, dw_w, dw_b, (bf16*)pgb);
  k_fc2<<<2304,256,0,stream>>>(pgb, xm, Wp2, fc2_b, (float*)d_out);
}

// Round 18
// 833.321 us; speedup vs baseline: 1.0981x; 1.0981x over previous
//
#include <hip/hip_runtime.h>
#include <hip/hip_bf16.h>
#include <math.h>
#include <type_traits>

#define Bb 8
#define Cc 180
#define HWn 9216
#define PD 16
#define CRr 60
#define HID 360
#define H2 720
#define NF 49
#define SPL 9408   /* spectral plane stride in floats: 96*49*2 */
#define CONV_SCALE 0.01f
#define FFT_RES 0.15f
#define EPSLN 1e-5f
#define TWOPI_96 0.06544984694978735f

typedef __hip_bfloat16 bf16;
typedef unsigned short ushort;
typedef __attribute__((ext_vector_type(8))) short s8v;   // 8 bf16 (4 VGPRs) MFMA A/B frag
typedef __attribute__((ext_vector_type(4))) float f4v;   // MFMA C/D frag
struct us4 { ushort x,y,z,w; };

__device__ __forceinline__ float geluf(float x){ return 0.5f*x*(1.0f+erff(x*0.7071067811865476f)); }
__device__ __forceinline__ float sigm(float x){ return 1.0f/(1.0f+expf(-x)); }
__device__ __forceinline__ short f2bf(float f){
  unsigned u = __float_as_uint(f);
  u += 0x7fff + ((u>>16)&1);
  return (short)(u>>16);
}
__device__ __forceinline__ float bf2f(ushort u){ return __uint_as_float(((unsigned)u)<<16); }
__device__ __forceinline__ float wredsum(float v){
#pragma unroll
  for(int m=1;m<64;m<<=1) v += __shfl_xor(v,m,64);
  return v;
}

// ---------------- LN1 + transpose to (B,C,H,W) + fused plane-mean partials ----------------
__global__ void __launch_bounds__(256) k_ln1(const float* __restrict__ x, const float* __restrict__ g,
                      const float* __restrict__ be, float* __restrict__ ximg, float* __restrict__ m1){
  __shared__ float sb[32*Cc];
  int b = blockIdx.x / 288;
  int n0 = (blockIdx.x % 288) * 32;
  int t = threadIdx.x;
  const float* src = x + (size_t)(b*HWn + n0)*Cc;
  for(int i=t;i<32*Cc;i+=256) sb[i]=src[i];
  __syncthreads();
  int w = t>>6, lane = t&63;
  for(int pi=0; pi<8; ++pi){
    int p = w*8+pi;
    float s=0.f, sq=0.f;
    for(int e=lane;e<Cc;e+=64){ float v=sb[p*Cc+e]; s+=v; sq+=v*v; }
    s = wredsum(s); sq = wredsum(sq);
    float mean = s*(1.0f/180.0f);
    float var = sq*(1.0f/180.0f) - mean*mean;
    float rstd = rsqrtf(var + EPSLN);
    for(int e=lane;e<Cc;e+=64){ float v=sb[p*Cc+e]; sb[p*Cc+e] = (v-mean)*rstd*g[e]+be[e]; }
  }
  __syncthreads();
  if(t<Cc){
    float s=0.f;
#pragma unroll 8
    for(int p=0;p<32;p++) s += sb[p*Cc+t];
    atomicAdd(&m1[b*Cc+t], s*(1.0f/9216.0f));
  }
  for(int i=t;i<32*Cc;i+=256){
    int c = i/32, p = i%32;
    ximg[(size_t)(b*Cc+c)*HWn + n0 + p] = sb[p*Cc+c];
  }
}

// ---------------- small: gates, hdn->dk, fft bias ----------------
__global__ void k_small(const float* __restrict__ m1, const float* __restrict__ gate_w,
   const float* __restrict__ gate_b, const float* __restrict__ dwc_w1, const float* __restrict__ dwc_b1,
   const float* __restrict__ dwc_w2, const float* __restrict__ dwc_b2, const float* __restrict__ band_b,
   float* __restrict__ gates, float* __restrict__ dkb, float* __restrict__ biasb){
  int b = threadIdx.x;
  if(b>=Bb) return;
  const float* m = m1 + b*Cc;
  float gv[3];
  for(int k=0;k<3;k++){ float a=gate_b[k]; for(int c=0;c<Cc;c++) a+=m[c]*gate_w[k*Cc+c]; gv[k]=sigm(a);}
  float e0=expf(gv[0]), e1=expf(gv[1]), e2=expf(gv[2]); float inv=1.0f/(e0+e1+e2);
  float g0=e0*inv,g1=e1*inv,g2=e2*inv;
  gates[b*3+0]=g0; gates[b*3+1]=g1; gates[b*3+2]=g2;
  float hd[8];
  for(int j=0;j<8;j++){ float a=dwc_b1[j]; for(int c=0;c<PD;c++) a+=m[c]*dwc_w1[j*PD+c]; hd[j]=geluf(a);}
  for(int i=0;i<144;i++){ float a=dwc_b2[i]; for(int j=0;j<8;j++) a+=hd[j]*dwc_w2[i*8+j]; dkb[b*144+i]=a; }
  for(int d=0;d<Cc;d++) biasb[b*Cc+d] = g0*band_b[0*Cc+d]+g1*band_b[1*Cc+d]+g2*band_b[2*Cc+d];
}

// ------- pack weights to bf16 + DFT twiddle matrices (+ zero m1/gapb accumulators) -------
// Wg1, Wg2, Wbk, Wpa, Wp2 packed FRAGMENT-MAJOR: each MFMA B-fragment load is lane-contiguous 1KB.
// Wg frag index: f = ((ct*9+tap)*NCHUNK+ch)*4+ts ; elem (lane,q): co=ct*64+ts*16+lr, ci=ch*32+kq*8+q
__global__ void __launch_bounds__(256) k_packw(const float* __restrict__ w1, const float* __restrict__ w2,
    const float* __restrict__ fw1, const float* __restrict__ fw2, const float* __restrict__ aw,
    const float* __restrict__ bw,
    ushort* __restrict__ Wg1, ushort* __restrict__ Wg2, ushort* __restrict__ Wp1,
    ushort* __restrict__ Wp2, ushort* __restrict__ Wpa, ushort* __restrict__ Wbk,
    ushort* __restrict__ Bfx, ushort* __restrict__ Tm, ushort* __restrict__ Bix,
    float* __restrict__ m1z, float* __restrict__ gapz){
  int t = blockIdx.x*256 + threadIdx.x;
  if(t < Bb*Cc){ m1z[t]=0.f; gapz[t]=0.f; }
  // Wg1 (conv1, ct=0, NCHUNK=6): f = (tap*6+ch)*4+ts ; 216 frags x 512 = 110592
  if(t < 110592){
    int q=t&7; int lane=(t>>3)&63; int f=t>>9;
    int kq=lane>>4, lr=lane&15;
    int ts=f&3; int rest=f>>2; int ch=rest%6; int tap=rest/6;
    int co=ts*16+lr, ci=ch*32+kq*8+q;
    float v=(co<CRr&&ci<Cc)? w1[((size_t)(co*Cc+ci))*9+tap]:0.f;
    Wg1[t]=(ushort)f2bf(v);
  }
  // Wg2 (conv2, 3 ct, NCHUNK=2): f = ((ct*9+tap)*2+ch)*4+ts ; 216 frags x 512 = 110592
  if(t < 110592){
    int q=t&7; int lane=(t>>3)&63; int f=t>>9;
    int kq=lane>>4, lr=lane&15;
    int ts=f&3; int rest=f>>2; int ch=rest&1; rest>>=1; int tap=rest%9; int ct=rest/9;
    int co=ct*64+ts*16+lr, ci=ch*32+kq*8+q;
    float v=(co<Cc&&ci<CRr)? w2[((size_t)(co*CRr+ci))*9+tap]:0.f;
    Wg2[t]=(ushort)f2bf(v);
  }
  if(t < 768*192){
    int j=t/192, k=t%192;
    Wp1[t] = (ushort)f2bf((j<H2 && k<Cc)? fw1[(size_t)j*Cc+k] : 0.f);
  }
  // Wp2 fragment-major: t = (ct*12+k6)*512 + lane*8 + q ; d=ct*16+lr, c=kq*8+k6*32+q
  if(t < 192*384){
    int q = t&7; int rest = t>>3;
    int lane = rest&63; rest >>= 6;
    int kq = lane>>4, lr = lane&15;
    int k6 = rest%12; int ct = rest/12;
    int d = ct*16+lr, c = kq*8 + k6*32 + q;
    Wp2[t] = (ushort)f2bf((d<Cc && c<HID)? fw2[(size_t)d*HID+c] : 0.f);
  }
  // Wpa fragment-major: t = ((jt*6+k6)*4+kq)*128 + lr*8 + q ; d=jt*16+lr, c=kq*8+k6*32+q
  if(t < 192*192){
    int q = t&7; int rest = t>>3;
    int lr = rest&15; rest >>= 4;
    int kq = rest&3; rest >>= 2;
    int k6 = rest%6; int jt = rest/6;
    int d = jt*16+lr, c = kq*8 + k6*32 + q;
    Wpa[t] = (ushort)f2bf((d<Cc && c<Cc)? aw[(size_t)d*Cc+c] : 0.f);
  }
  // Wbk fragment-major: t = (((k*12+ts)*6+k6)*4+kq)*128 + lr*8 + q ; d=ts*16+lr, c=kq*8+k6*32+q
  if(t < 3*192*192){
    int q = t&7; int rest = t>>3;
    int lr = rest&15; rest >>= 4;
    int kq = rest&3; rest >>= 2;
    int k6 = rest%6; rest /= 6;
    int ts = rest%12; int k = rest/12;
    int d = ts*16+lr, c = kq*8 + k6*32 + q;
    Wbk[t] = (ushort)f2bf((d<Cc && c<Cc)? bw[((size_t)k*Cc + d)*Cc + c] : 0.f);
  }
  if(t < 112*96){
    int n=t/96, k=t%96;
    float v=0.f;
    if(n<98){
      int kx=n>>1; int m=(k*kx)%96; float th=(float)m*TWOPI_96;
      v = ((n&1)? -sinf(th) : cosf(th)) * (1.0f/96.0f);
    }
    Bfx[t] = (ushort)f2bf(v);
  }
  if(t < 96*192){
    int r=t/192, k=t%192;
    int c=k>>1; int m=(r*c)%96; float th=(float)m*TWOPI_96;
    float v = (k&1)? sinf(th) : cosf(th);
    Tm[t] = (ushort)f2bf(v);
  }
  if(t < 96*128){
    int n=t/128, k=t%128;
    float v=0.f;
    if(k<98){
      int kx=k>>1; float wgt=(kx==0||kx==48)?1.0f:2.0f;
      int m=(n*kx)%96; float th=(float)m*TWOPI_96;
      v = ((k&1)? -wgt*sinf(th) : wgt*cosf(th)) * (1.0f/96.0f);
    }
    Bix[t] = (ushort)f2bf(v);
  }
}

// ------- pack plk + per-batch dynamic depthwise into Wdk[b][co][13ky][7kxp][2tl*16ci] bf16 -------
__global__ void __launch_bounds__(256) k_packplk(const float* __restrict__ plk,
    const float* __restrict__ dkb, ushort* __restrict__ Wdk){
  int t = blockIdx.x*256 + threadIdx.x;
  if(t >= Bb*PD*13*7*32) return;
  int k = t & 31; int rest = t >> 5;
  int kxp = rest % 7; rest /= 7;
  int ky = rest % 13; rest /= 13;
  int co = rest % PD; int b = rest / PD;
  int tl = k >> 4, ci = k & 15;
  int kx = kxp*2 + tl;
  float v = 0.f;
  if(kx < 13){
    v = plk[((size_t)(co*PD+ci)*13 + ky)*13 + kx];
    if(ci==co && ky>=5 && ky<8 && kx>=5 && kx<8)
      v += dkb[b*144 + co*9 + (ky-5)*3 + (kx-5)];
  }
  Wdk[t] = (ushort)f2bf(v);
}

// ---------------- fused forward 2D rDFT (per plane), MFMA, 8 waves ----------------
__global__ void __launch_bounds__(512) k_fft_fwd(const float* __restrict__ ximg,
    const ushort* __restrict__ Bfx, const ushort* __restrict__ Tm, float* __restrict__ S){
  __shared__ __align__(16) short Asi[96*104];
  __shared__ __align__(16) short Bv[112*200];
  int bc = blockIdx.x; int t = threadIdx.x;
  int w=t>>6, lane=t&63, kq=lane>>4, lr=lane&15;
  const float* src = ximg + (size_t)bc*HWn;
  for(int i=t;i<1152;i+=512){
    int y=i/12, seg=i%12;
    float4 v0 = *(const float4*)(src + y*96 + seg*8);
    float4 v1 = *(const float4*)(src + y*96 + seg*8 + 4);
    s8v pk;
    pk[0]=f2bf(v0.x); pk[1]=f2bf(v0.y); pk[2]=f2bf(v0.z); pk[3]=f2bf(v0.w);
    pk[4]=f2bf(v1.x); pk[5]=f2bf(v1.y); pk[6]=f2bf(v1.z); pk[7]=f2bf(v1.w);
    *(s8v*)&Asi[y*104+seg*8] = pk;
  }
  __syncthreads();
  for(int tile=w; tile<42; tile+=8){
    int mt=tile/7, nt=tile%7;
    f4v acc={};
#pragma unroll
    for(int ks=0;ks<3;ks++){
      s8v af = *(const s8v*)&Asi[(mt*16+lr)*104 + kq*8 + ks*32];
      s8v bf = *(const s8v*)&Bfx[(size_t)(nt*16+lr)*96 + kq*8 + ks*32];
      acc = __builtin_amdgcn_mfma_f32_16x16x32_bf16(af,bf,acc,0,0,0);
    }
    int n = nt*16+lr;
    float sgn = (n&1)? -1.f : 1.f;
#pragma unroll
    for(int reg=0;reg<4;reg++){
      int y = mt*16+kq*4+reg;
      float v = acc[reg];
      float p = __shfl_xor(v,1);
      unsigned pack = ((unsigned)(ushort)f2bf(sgn*p)<<16) | (ushort)(unsigned short)f2bf(v);
      *(unsigned*)&Bv[n*200 + 2*y] = pack;
    }
  }
  __syncthreads();
  float* dst = S + (size_t)bc*SPL;
  for(int tile=w; tile<42; tile+=8){
    int mt=tile/7, nt=tile%7;
    f4v acc={};
#pragma unroll
    for(int ks=0;ks<6;ks++){
      s8v af = *(const s8v*)&Tm[(size_t)(mt*16+lr)*192 + kq*8 + ks*32];
      s8v bf = *(const s8v*)&Bv[(nt*16+lr)*200 + kq*8 + ks*32];
      acc = __builtin_amdgcn_mfma_f32_16x16x32_bf16(af,bf,acc,0,0,0);
    }
    int n = nt*16+lr;
    if(n<98){
#pragma unroll
      for(int reg=0;reg<4;reg++){
        int ky = mt*16+kq*4+reg;
        dst[ky*98 + n] = acc[reg];
      }
    }
  }
}

// ---------------- fused inverse 2D rDFT + combine (per plane), MFMA, 8 waves ----------------
__global__ void __launch_bounds__(512) k_fft_inv(float* __restrict__ S, const float* __restrict__ ximg,
    const float* __restrict__ biasb, const ushort* __restrict__ Tm, const ushort* __restrict__ Bix){
  __shared__ __align__(16) short Bv[112*200];
  __shared__ __align__(16) short T2s[96*136];
  int bd = blockIdx.x; int t=threadIdx.x;
  int w=t>>6, lane=t&63, kq=lane>>4, lr=lane&15;
  int b = bd/Cc, d = bd%Cc;
  float* pl = S + (size_t)bd*SPL;
  for(int i=t;i<1400;i+=512) ((unsigned*)&Bv[98*200])[i] = 0u;
  for(int i=t;i<1152;i+=512){ int y=i/12, c=i%12; *(unsigned*)&T2s[y*136+112+c*2] = 0u; }
  for(int i2=t;i2<4704;i2+=512){
    int idx = i2*2;
    float2 v = *(const float2*)(pl + idx);
    int ky = idx/98, n = idx%98;     // n even
    unsigned pack0 = ((unsigned)(ushort)f2bf(-v.y)<<16) | (ushort)(unsigned short)f2bf(v.x);
    unsigned pack1 = ((unsigned)(ushort)f2bf( v.x)<<16) | (ushort)(unsigned short)f2bf(v.y);
    *(unsigned*)&Bv[n*200 + 2*ky]     = pack0;
    *(unsigned*)&Bv[(n+1)*200 + 2*ky] = pack1;
  }
  __syncthreads();
  for(int tile=w; tile<42; tile+=8){
    int mt=tile/7, nt=tile%7;
    f4v acc={};
#pragma unroll
    for(int ks=0;ks<6;ks++){
      s8v af = *(const s8v*)&Tm[(size_t)(mt*16+lr)*192 + kq*8 + ks*32];
      s8v bf = *(const s8v*)&Bv[(nt*16+lr)*200 + kq*8 + ks*32];
      acc = __builtin_amdgcn_mfma_f32_16x16x32_bf16(af,bf,acc,0,0,0);
    }
    int n = nt*16+lr;
#pragma unroll
    for(int reg=0;reg<4;reg++){
      int y = mt*16+kq*4+reg;
      T2s[y*136 + n] = f2bf(acc[reg]);
    }
  }
  __syncthreads();
  float bias = biasb[b*Cc+d];
  const float* xs = ximg + (size_t)bd*HWn;
  ushort* po = (ushort*)pl;
  for(int tile=w; tile<36; tile+=8){
    int mt=tile/6, nt=tile%6;
    f4v acc={};
#pragma unroll
    for(int ks=0;ks<4;ks++){
      s8v af = *(const s8v*)&T2s[(mt*16+lr)*136 + kq*8 + ks*32];
      s8v bf = *(const s8v*)&Bix[(size_t)(nt*16+lr)*128 + kq*8 + ks*32];
      acc = __builtin_amdgcn_mfma_f32_16x16x32_bf16(af,bf,acc,0,0,0);
    }
    int xx = nt*16+lr;
#pragma unroll
    for(int reg=0;reg<4;reg++){
      int y = mt*16+kq*4+reg;
      int o = y*96+xx;
      po[o] = (ushort)f2bf(xs[o] + FFT_RES*(acc[reg] + bias));
    }
  }
}

// ---------------- band channel mix as MFMA GEMM, IN-PLACE, 8 waves, Wbk fragment-major ----------------
__global__ void __launch_bounds__(512) k_bandmixm(float* __restrict__ S, const ushort* __restrict__ Wbk,
                          const float* __restrict__ gates){
  __shared__ __align__(16) short Bs[64*200];
  int f2base = blockIdx.x*64;
  int b = blockIdx.y;
  int t = threadIdx.x;
  int w=t>>6, lane=t&63, kq=lane>>4, lr=lane&15;
  int wr = w&3, chh = w>>2;
  for(int i=t;i<8*192;i+=512){
    int rblk=i&7, kk=i>>3;
    int r0=rblk*8;
    if(kk<Cc){
      const float* src = S + (size_t)(b*Cc+kk)*SPL + f2base + r0;
      float4 v0 = *(const float4*)src;
      float4 v1 = *(const float4*)(src+4);
      Bs[(r0+0)*200+kk]=f2bf(v0.x); Bs[(r0+1)*200+kk]=f2bf(v0.y);
      Bs[(r0+2)*200+kk]=f2bf(v0.z); Bs[(r0+3)*200+kk]=f2bf(v0.w);
      Bs[(r0+4)*200+kk]=f2bf(v1.x); Bs[(r0+5)*200+kk]=f2bf(v1.y);
      Bs[(r0+6)*200+kk]=f2bf(v1.z); Bs[(r0+7)*200+kk]=f2bf(v1.w);
    } else {
#pragma unroll
      for(int q=0;q<8;q++) Bs[(r0+q)*200+kk]=0;
    }
  }
  unsigned bmask;
  {
    int col = f2base + lane;
    int ky = col/98, n = col%98, kx = n>>1;
    float yy = -1.0f + 2.0f*(float)ky/95.0f;
    float xxf = (float)kx/48.0f;
    float rr = sqrtf(yy*yy+xxf*xxf);
    int k = (rr<=0.25f)?0:((rr<=0.6f)?1:2);
    unsigned m = 1u<<k;
#pragma unroll
    for(int s=1;s<64;s<<=1) m |= __shfl_xor(m,s);
    bmask = m;
  }
  int kb[4]; float gv[4];
#pragma unroll
  for(int reg=0;reg<4;reg++){
    int col = f2base + wr*16 + kq*4 + reg;
    int ky = col/98, n = col%98, kx = n>>1;
    float yy = -1.0f + 2.0f*(float)ky/95.0f;
    float xxf = (float)kx/48.0f;
    float rr = sqrtf(yy*yy+xxf*xxf);
    kb[reg] = (rr<=0.25f)?0:((rr<=0.6f)?1:2);
    gv[reg] = gates[b*3+kb[reg]];
  }
  __syncthreads();
  s8v af[6];
#pragma unroll
  for(int k6=0;k6<6;k6++) af[k6] = *(const s8v*)&Bs[(wr*16+lr)*200 + kq*8 + k6*32];
  float res[6][4];
  for(int k=0;k<3;k++){
    if(!(bmask&(1u<<k))) continue;
    for(int j=0;j<6;j++){
      int ts = chh*6 + j;
      f4v acc={};
#pragma unroll
      for(int k6=0;k6<6;k6++){
        s8v wf = *(const s8v*)&Wbk[((size_t)((k*12+ts)*6 + k6))*512 + lane*8];
        acc = __builtin_amdgcn_mfma_f32_16x16x32_bf16(af[k6],wf,acc,0,0,0);
      }
#pragma unroll
      for(int reg=0;reg<4;reg++) if(kb[reg]==k) res[j][reg]=gv[reg]*acc[reg];
    }
  }
#pragma unroll
  for(int j=0;j<6;j++){
    int d = (chh*6+j)*16+lr;
    if(d<Cc){
      float4 o; o.x=res[j][0]; o.y=res[j][1]; o.z=res[j][2]; o.w=res[j][3];
      *(float4*)(S + (size_t)(b*Cc+d)*SPL + f2base + wr*16 + kq*4) = o;
    }
  }
}

// ---------------- CAB 3x3 conv as implicit-GEMM MFMA, bf16 in/out,
//                  Wg FRAGMENT-MAJOR (lane-contiguous weight loads) ----------------
template<int NW, int CIN, int KPAD, int NCHUNK, bool ACT, bool OUTBF>
__global__ void __launch_bounds__(NW*64) k_cab(const ushort* __restrict__ xin, const ushort* __restrict__ Wg,
    const float* __restrict__ bias, ushort* __restrict__ out, int COUT, int istride,
    float* __restrict__ gapp){
  constexpr int NT = NW*64;
  constexpr int STILES = 12/NW;
  __shared__ short As[4*98*36];
  int y0 = blockIdx.x*2;
  int ct = blockIdx.y;
  int b  = blockIdx.z;
  int t = threadIdx.x;
  int w = t>>6, lane = t&63, kq = lane>>4, lr = lane&15;
  f4v acc[STILES][4] = {};
  for(int ch=0; ch<NCHUNK; ++ch){
    int ci0 = ch*32;
    __syncthreads();
    for(int u=t; u<4*12*32; u+=NT){
      int ci = u&31; int rest = u>>5; int seg = rest%12; int row = rest/12;
      int gy = y0 - 1 + row; int cig = ci0+ci;
      s8v v = {};
      if((unsigned)gy<96u && cig<CIN)
        v = *(const s8v*)&xin[(size_t)(b*CIN+cig)*istride + gy*96 + seg*8];
      int base = (row*98 + seg*8 + 1)*36 + ci;
#pragma unroll
      for(int q=0;q<8;q++) As[base + q*36] = v[q];
    }
    for(int u=t; u<4*2*32; u+=NT){
      int ci=u&31; int rest=u>>5; int e=rest&1; int row=rest>>1;
      As[(row*98 + (e?97:0))*36 + ci] = 0;
    }
    __syncthreads();
#pragma unroll
    for(int tap=0; tap<9; ++tap){
      int ky = tap/3, kx = tap%3;
      s8v bfr[4];
#pragma unroll
      for(int ts=0;ts<4;ts++)
        bfr[ts] = *(const s8v*)&Wg[((size_t)(((ct*9+tap)*NCHUNK+ch)*4+ts))*512 + lane*8];
#pragma unroll
      for(int s=0;s<STILES;s++){
        int mt = w + NW*s;
        int orow = mt/6, px = (mt%6)*16 + lr;
        s8v af = *(const s8v*)&As[((orow+ky)*98 + px + kx)*36 + kq*8];
#pragma unroll
        for(int ts=0;ts<4;ts++)
          acc[s][ts] = __builtin_amdgcn_mfma_f32_16x16x32_bf16(af, bfr[ts], acc[s][ts], 0,0,0);
      }
    }
  }
  if(OUTBF){
    __syncthreads();
    short* cT = As;
#pragma unroll
    for(int ts=0;ts<4;ts++){
      int cog = ct*64 + ts*16 + lr;
      float bb = (cog<COUT)? bias[cog] : 0.f;
#pragma unroll
      for(int s=0;s<STILES;s++){
        int mt = w + NW*s;
#pragma unroll
        for(int reg=0;reg<4;reg++){
          int px = mt*16 + kq*4 + reg;
          float v = acc[s][ts][reg] + bb;
          if(ACT) v = geluf(v);
          cT[(ts*16+lr)*200 + px] = f2bf(v);
        }
      }
    }
    __syncthreads();
    for(int i=t;i<64*24;i+=NT){
      int co=i/24, seg=i%24;
      int cog = ct*64+co;
      if(cog<COUT)
        *(s8v*)&out[(size_t)(b*COUT+cog)*HWn + y0*96 + seg*8] = *(const s8v*)&cT[co*200+seg*8];
    }
  } else {
    float* cF = (float*)As;
    for(int h=0;h<2;h++){
      __syncthreads();
#pragma unroll
      for(int tt=0;tt<2;tt++){
        int ts = 2*h+tt;
        int cog = ct*64 + ts*16 + lr;
        float bb = (cog<COUT)? bias[cog] : 0.f;
#pragma unroll
        for(int s=0;s<STILES;s++){
          int mt = w + NW*s;
#pragma unroll
          for(int reg=0;reg<4;reg++){
            int px = mt*16 + kq*4 + reg;
            cF[(tt*16+lr)*200 + px] = acc[s][ts][reg] + bb;
          }
        }
      }
      __syncthreads();
      for(int i=t;i<32*24;i+=NT){
        int co=i/24, seg=i%24;
        int cog = ct*64 + h*32 + co;
        if(cog<COUT){
          s8v pk;
#pragma unroll
          for(int q=0;q<8;q++) pk[q] = f2bf(cF[co*200+seg*8+q]);
          *(s8v*)&out[(size_t)(b*COUT+cog)*HWn + y0*96 + seg*8] = pk;
        }
      }
      if(gapp){
        for(int row=w; row<32; row+=NW){
          int cog = ct*64 + h*32 + row;
          float s=0.f;
#pragma unroll
          for(int px=lane;px<192;px+=64) s += cF[row*200+px];
          s = wredsum(s);
          if(lane==0 && cog<COUT) atomicAdd(&gapp[(size_t)b*COUT+cog], s*(1.0f/9216.0f));
        }
      }
    }
  }
}

// ---------------- ECA ----------------
__global__ void k_eca(const float* __restrict__ gap, const float* __restrict__ ew, float* __restrict__ s){
  int i = blockIdx.x*blockDim.x + threadIdx.x;
  if(i>=Bb*Cc) return;
  int b=i/Cc, c=i%Cc;
  float z=0.f;
  for(int j=0;j<5;j++){ int cc=c-2+j; if(cc>=0&&cc<Cc) z+=gap[b*Cc+cc]*ew[j]; }
  s[i]=sigm(z);
}

// ------- plk 13x13 + fused dynamic dw3x3 as implicit-GEMM MFMA (tap-pair K=32), 6 waves -------
__global__ void __launch_bounds__(384) k_plkm(const float* __restrict__ ximg,
    const ushort* __restrict__ Wdk, float* __restrict__ attn){
  __shared__ short As[15*109*20];
  int y0 = blockIdx.x*3;
  int b  = blockIdx.y;
  int t = threadIdx.x;
  int w = t>>6, lane = t&63, kq = lane>>4, lr = lane&15;
  for(int i=t;i<PD*15*109;i+=384){
    int ci = i/(15*109); int rem = i%(15*109);
    int row = rem/109, pxh = rem%109;
    int gy = y0 + row - 6, gx = pxh - 6;
    short sv = 0;
    if((unsigned)gy<96u && (unsigned)gx<96u)
      sv = f2bf(ximg[(size_t)(b*Cc+ci)*HWn + gy*96 + gx]);
    As[(row*109+pxh)*20 + ci] = sv;
  }
  __syncthreads();
  f4v acc[3] = {};
  const ushort* wb = Wdk + ((size_t)(b*PD+lr)*13)*7*32 + kq*8;
  for(int ky=0;ky<13;ky++){
#pragma unroll
    for(int kxp=0;kxp<7;kxp++){
      s8v bfr = *(const s8v*)(wb + (ky*7+kxp)*32);
#pragma unroll
      for(int ti=0;ti<3;ti++){
        int mt = w + 6*ti;
        int yo = mt/6, o = (mt%6)*16;
        s8v af = *(const s8v*)&As[((yo+ky)*109 + o + lr + 2*kxp + (kq>>1))*20 + (kq&1)*8];
        acc[ti] = __builtin_amdgcn_mfma_f32_16x16x32_bf16(af, bfr, acc[ti], 0,0,0);
      }
    }
  }
#pragma unroll
  for(int ti=0;ti<3;ti++){
    int mt = w + 6*ti;
    int yo = mt/6, o = (mt%6)*16 + kq*4;
    float4 ov; ov.x=acc[ti][0]; ov.y=acc[ti][1]; ov.z=acc[ti][2]; ov.w=acc[ti][3];
    *(float4*)&attn[(size_t)(b*PD+lr)*HWn + (y0+yo)*96 + o] = ov;
  }
}

// ---------------- aggr MFMA GEMM, 8 waves, Wpa fragment-major; + residual + LN2 ----------------
__global__ void __launch_bounds__(512) k_aggrm(const float* __restrict__ x, const float* __restrict__ attn,
   const float* __restrict__ ximg, const ushort* __restrict__ ycab, const ushort* __restrict__ Wpa,
   const float* __restrict__ aggb, const float* __restrict__ svec,
   const float* __restrict__ g2, const float* __restrict__ b2,
   float* __restrict__ xm, ushort* __restrict__ xn2){
  __shared__ __align__(16) float smem[64*188];
  short* As = (short*)smem;
  float* cF = smem;
  int rt = blockIdx.x;
  int t = threadIdx.x;
  int w = t>>6, lane = t&63, kq = lane>>4, lr = lane&15;
  int grow0 = rt*64; int b = grow0/HWn; int n0 = grow0%HWn;
  for(int i=t;i<8*192;i+=512){
    int rblk=i&7, kk=i>>3;
    int r0=rblk*8;
    if(kk<Cc){
      const float* src = (kk<PD)? attn + (size_t)(b*PD+kk)*HWn + n0 + r0
                                : ximg + (size_t)(b*Cc+kk)*HWn + n0 + r0;
      float4 v0 = *(const float4*)src;
      float4 v1 = *(const float4*)(src+4);
      As[(r0+0)*200+kk]=f2bf(v0.x); As[(r0+1)*200+kk]=f2bf(v0.y);
      As[(r0+2)*200+kk]=f2bf(v0.z); As[(r0+3)*200+kk]=f2bf(v0.w);
      As[(r0+4)*200+kk]=f2bf(v1.x); As[(r0+5)*200+kk]=f2bf(v1.y);
      As[(r0+6)*200+kk]=f2bf(v1.z); As[(r0+7)*200+kk]=f2bf(v1.w);
    } else {
#pragma unroll
      for(int q=0;q<8;q++) As[(r0+q)*200+kk]=0;
    }
  }
  __syncthreads();
  int wr = w&3, ch = w>>2;
  s8v af[6];
  int arow=(wr*16+lr)*200 + kq*8;
#pragma unroll
  for(int k6=0;k6<6;k6++) af[k6] = *(const s8v*)&As[arow + k6*32];
  f4v acc[6]={};
#pragma unroll
  for(int j=0;j<6;j++){
    int jt = ch*6+j;
#pragma unroll
    for(int k6=0;k6<6;k6++){
      s8v wf = *(const s8v*)&Wpa[((size_t)(jt*6 + k6))*512 + lane*8];
      acc[j]=__builtin_amdgcn_mfma_f32_16x16x32_bf16(af[k6],wf,acc[j],0,0,0);
    }
  }
  __syncthreads();
#pragma unroll
  for(int j=0;j<6;j++){
    int jc = (ch*6+j)*16 + lr;
    if(jc<Cc){
      float bb = aggb[jc];
      float sv = CONV_SCALE*svec[b*Cc+jc];
      const ushort* yrow = ycab + (size_t)(b*Cc+jc)*HWn + n0;
#pragma unroll
      for(int reg=0;reg<4;reg++){
        int m = wr*16 + kq*4 + reg;
        cF[m*188+jc] = acc[j][reg] + bb + sv*bf2f(yrow[m]);
      }
    }
  }
  __syncthreads();
  for(int r=0;r<8;r++){
    int m = w*8 + r;
    size_t baseo = (size_t)(grow0+m)*Cc;
    float vbuf[3];
    float s=0.f, sq=0.f;
#pragma unroll
    for(int it=0;it<3;it++){
      int e = lane + it*64;
      float v = (e<Cc)? cF[m*188+e] + x[baseo+e] : 0.f;
      vbuf[it]=v; s+=v; sq+=v*v;
    }
    s=wredsum(s); sq=wredsum(sq);
    float mean = s*(1.0f/180.0f);
    float var = sq*(1.0f/180.0f) - mean*mean;
    float rstd = rsqrtf(var + EPSLN);
    ushort* orow = xn2 + (size_t)(grow0+m)*192;
#pragma unroll
    for(int it=0;it<3;it++){
      int e = lane + it*64;
      if(e<Cc){
        float v = vbuf[it];
        xm[baseo+e] = v;
        orow[e] = (ushort)f2bf((v-mean)*rstd*g2[e]+b2[e]);
      } else {
        orow[e] = 0;
      }
    }
  }
}

// -------- fc1 MFMA: W-tile staged to LDS via coalesced s8v copies --------
__global__ void __launch_bounds__(256) k_fc1(const ushort* __restrict__ xn2,
    const ushort* __restrict__ Wp, const float* __restrict__ fb, ushort* __restrict__ t1){
  __shared__ __align__(16) short Ws[64*200];
  int rt = blockIdx.x;
  int t = threadIdx.x;
  int w = t>>6, lane = t&63, kq = lane>>4, lr = lane&15;
  int grow0 = rt*64;
  int bb_ = grow0/HWn, n0 = grow0%HWn;
  s8v af[6];
  const ushort* arow = xn2 + (size_t)(grow0 + w*16 + lr)*192 + kq*8;
#pragma unroll
  for(int k6=0;k6<6;k6++) af[k6] = *(const s8v*)(arow + k6*32);
  int mcol = n0 + w*16 + kq*4;
  for(int ct=0; ct<12; ++ct){
    __syncthreads();
    const s8v* src = (const s8v*)(Wp + (size_t)ct*64*192);
#pragma unroll
    for(int q=0;q<6;q++){
      int i = t + q*256;
      int j = i/24, seg = i%24;
      *(s8v*)&Ws[j*200 + seg*8] = src[i];
    }
    __syncthreads();
    f4v acc[4]={};
#pragma unroll
    for(int k6=0;k6<6;k6++){
#pragma unroll
      for(int ts=0;ts<4;ts++){
        s8v wf = *(const s8v*)&Ws[(ts*16+lr)*200 + kq*8 + k6*32];
        acc[ts]=__builtin_amdgcn_mfma_f32_16x16x32_bf16(af[k6],wf,acc[ts],0,0,0);
      }
    }
#pragma unroll
    for(int ts=0;ts<4;ts++){
      int jc = ct*64 + ts*16 + lr;
      if(jc<H2){
        float bb = fb[jc];
        us4 pk;
        pk.x=(ushort)f2bf(acc[ts][0]+bb); pk.y=(ushort)f2bf(acc[ts][1]+bb);
        pk.z=(ushort)f2bf(acc[ts][2]+bb); pk.w=(ushort)f2bf(acc[ts][3]+bb);
        *(us4*)&t1[((size_t)(bb_*H2+jc))*HWn + mcol] = pk;
      }
    }
  }
}

// ---------------- depthwise 3x3 on t1 + GLU -> pg (B,360,HW) bf16 ----------------
__global__ void __launch_bounds__(256) k_dwglu(const bf16* __restrict__ t1, const float* __restrict__ dww,
    const float* __restrict__ dwb, bf16* __restrict__ pg){
  __shared__ float ta[34*34];
  __shared__ float tg[34*34];
  int tile_id=blockIdx.x; int c=blockIdx.y; int b=blockIdx.z;
  int ty0=(tile_id/3)*32, tx0=(tile_id%3)*32;
  int t=threadIdx.x;
  int px0=(t%16)*2, py0=(t/16)*2;
  for(int i=t;i<34*34;i+=256){
    int ly=i/34, lx=i%34; int gy=ty0+ly-1, gx=tx0+lx-1;
    bool ok=((unsigned)gy<96u&&(unsigned)gx<96u);
    ta[i]= ok? __bfloat162float(t1[((size_t)(b*H2+c)*96+gy)*96+gx]) :0.f;
    tg[i]= ok? __bfloat162float(t1[((size_t)(b*H2+c+HID)*96+gy)*96+gx]) :0.f;
  }
  __syncthreads();
  float wp[9],wg[9];
#pragma unroll
  for(int i=0;i<9;i++){ wp[i]=dww[c*9+i]; wg[i]=dww[(c+HID)*9+i]; }
  float bp=dwb[c], bg=dwb[c+HID];
#pragma unroll
  for(int oy=0;oy<2;oy++)
#pragma unroll
    for(int ox=0;ox<2;ox++){
      float p=bp,g=bg;
#pragma unroll
      for(int ky=0;ky<3;ky++)
#pragma unroll
        for(int kx=0;kx<3;kx++){
          p+=wp[ky*3+kx]*ta[(py0+oy+ky)*34+px0+ox+kx];
          g+=wg[ky*3+kx]*tg[(py0+oy+ky)*34+px0+ox+kx];
        }
      float val = p * g * sigm(g);
      pg[((size_t)(b*HID+c)*96 + ty0+py0+oy)*96 + tx0+px0+ox] = __float2bfloat16(val);
    }
}

// ---------------- fc2 MFMA + residual -> out (B,N,C); BM=32, XOR-swizzled A staging,
//                  Wp2 FRAGMENT-MAJOR (lane-contiguous weight loads) ----------------
__global__ void __launch_bounds__(256) k_fc2(const ushort* __restrict__ pg, const float* __restrict__ xm,
    const ushort* __restrict__ Wp, const float* __restrict__ fb, float* __restrict__ out){
  __shared__ __align__(16) short As[32*392];
  float* cF = (float*)As;
  int rt = blockIdx.x;
  int t = threadIdx.x;
  int w = t>>6, lane = t&63, kq = lane>>4, lr = lane&15;
  int grow0 = rt*32; int b = grow0/HWn; int n0 = grow0%HWn;
  for(int i=t;i<4*HID;i+=256){
    int rblk = i&3; int kc = i>>2;
    int r0 = rblk*8;
    s8v v = *(const s8v*)&pg[((size_t)(b*HID+kc))*HWn + n0 + r0];
    int kcs = kc ^ (rblk<<3);
#pragma unroll
    for(int q=0;q<8;q++) As[(r0+q)*392 + kcs] = v[q];
  }
  for(int i=t;i<32*24;i+=256){
    int r = i/24, kc = 360 + i%24;
    As[r*392 + (kc ^ ((r>>3)<<3))] = 0;
  }
  __syncthreads();
  int mt = w&1;
  int row = mt*16 + lr;
  int rb = row>>3;
  s8v af[12];
#pragma unroll
  for(int k6=0;k6<12;k6++)
    af[k6] = *(const s8v*)&As[row*392 + ((kq ^ rb)<<3) + k6*32];
  f4v acc[6]={};
#pragma unroll
  for(int j=0;j<6;j++){
    int ct = (w>>1) + 2*j;
#pragma unroll
    for(int k6=0;k6<12;k6++){
      s8v wf = *(const s8v*)&Wp[(size_t)(ct*12 + k6)*512 + lane*8];
      acc[j]=__builtin_amdgcn_mfma_f32_16x16x32_bf16(af[k6],wf,acc[j],0,0,0);
    }
  }
  __syncthreads();
#pragma unroll
  for(int j=0;j<6;j++){
    int ct = (w>>1) + 2*j;
    int jc = ct*16 + lr;
    if(jc<Cc){
      float bb = fb[jc];
#pragma unroll
      for(int reg=0;reg<4;reg++){
        int m = mt*16 + kq*4 + reg;
        cF[m*Cc + jc] = acc[j][reg] + bb;
      }
    }
  }
  __syncthreads();
  size_t base = (size_t)grow0*Cc;
  for(int i=t;i<32*Cc;i+=256){
    out[base+i] = xm[base+i] + cF[i];
  }
}

extern "C" void kernel_launch(void* const* d_in, const int* in_sizes, int n_in,
                              void* d_out, int out_size, void* d_ws, size_t ws_size,
                              hipStream_t stream){
  (void)in_sizes; (void)n_in; (void)out_size; (void)ws_size;
  const float* x     = (const float*)d_in[0];
  const float* ln1_g = (const float*)d_in[3];
  const float* ln1_b = (const float*)d_in[4];
  const float* band_w= (const float*)d_in[5];
  const float* band_b= (const float*)d_in[6];
  const float* gate_w= (const float*)d_in[7];
  const float* gate_b= (const float*)d_in[8];
  const float* cab_w1= (const float*)d_in[9];
  const float* cab_b1= (const float*)d_in[10];
  const float* cab_w2= (const float*)d_in[11];
  const float* cab_b2= (const float*)d_in[12];
  const float* eca_w = (const float*)d_in[13];
  const float* plkw  = (const float*)d_in[14];
  const float* dwc_w1= (const float*)d_in[15];
  const float* dwc_b1= (const float*)d_in[16];
  const float* dwc_w2= (const float*)d_in[17];
  const float* dwc_b2= (const float*)d_in[18];
  const float* aggr_w= (const float*)d_in[19];
  const float* aggr_b= (const float*)d_in[20];
  const float* ln2_g = (const float*)d_in[21];
  const float* ln2_b = (const float*)d_in[22];
  const float* fc1_w = (const float*)d_in[23];
  const float* fc1_b = (const float*)d_in[24];
  const float* dw_w  = (const float*)d_in[25];
  const float* dw_b  = (const float*)d_in[26];
  const float* fc2_w = (const float*)d_in[27];
  const float* fc2_b = (const float*)d_in[28];

  float* ws = (float*)d_ws;
  float* xm   = ws;                      // 13,271,040
  float* m1   = ws + 13271040;
  float* gates= ws + 13272480;
  float* dkb  = ws + 13272512;
  float* biasb= ws + 13273664;
  float* gapb = ws + 13275104;
  float* svec = ws + 13276544;
  ushort* Wg1 = (ushort*)(ws + 13278000);
  ushort* Wg2 = (ushort*)(ws + 13333296);
  ushort* Wp1 = (ushort*)(ws + 13388592);
  ushort* Wp2 = (ushort*)(ws + 13462320);
  ushort* Wpa = (ushort*)(ws + 13499184);
  ushort* Bfx = (ushort*)(ws + 13517616);
  ushort* Tmw = (ushort*)(ws + 13522992);
  ushort* Bix = (ushort*)(ws + 13532208);
  ushort* Wbk = (ushort*)(ws + 13538352);
  ushort* Wdk = (ushort*)(ws + 13593648);
  float* big  = ws + 13780096;
  float* ximg = big;
  float* spec = big + 13271040;
  ushort* mid = (ushort*)(big + 26818560);
  float* attn = big + 29030400;
  ushort* ycab = (ushort*)spec;
  ushort* xn2 = (ushort*)(big + 30210048);
  ushort* t1  = (ushort*)big;
  float*  reg2= big + 26542080;
  ushort* pgb = (ushort*)reg2;

  k_packw<<<576,256,0,stream>>>(cab_w1, cab_w2, fc1_w, fc2_w, aggr_w, band_w,
                                Wg1, Wg2, Wp1, Wp2, Wpa, Wbk, Bfx, Tmw, Bix, m1, gapb);
  k_ln1<<<2304,256,0,stream>>>(x, ln1_g, ln1_b, ximg, m1);
  k_small<<<1,64,0,stream>>>(m1, gate_w, gate_b, dwc_w1, dwc_b1, dwc_w2, dwc_b2, band_b, gates, dkb, biasb);
  k_packplk<<<1456,256,0,stream>>>(plkw, dkb, Wdk);
  k_fft_fwd<<<1440,512,0,stream>>>(ximg, Bfx, Tmw, spec);
  k_bandmixm<<<dim3(147,Bb),512,0,stream>>>(spec, Wbk, gates);
  k_fft_inv<<<1440,512,0,stream>>>(spec, ximg, biasb, Tmw, Bix);
  k_cab<4, Cc, 192, 6, true,  true ><<<dim3(48,1,Bb),256,0,stream>>>((const ushort*)spec, Wg1, cab_b1, mid, CRr, 2*SPL, nullptr);
  k_cab<4, CRr, 64, 2, false, false><<<dim3(48,3,Bb),256,0,stream>>>(mid, Wg2, cab_b2, ycab, Cc, HWn, gapb);
  k_eca<<<6,256,0,stream>>>(gapb, eca_w, svec);
  k_plkm<<<dim3(32,Bb),384,0,stream>>>(ximg, Wdk, attn);
  k_aggrm<<<1152,512,0,stream>>>(x, attn, ximg, ycab, Wpa, aggr_b, svec, ln2_g, ln2_b, xm, xn2);
  k_fc1<<<1152,256,0,stream>>>(xn2, Wp1, fc1_b, t1);
  k_dwglu<<<dim3(9,HID,Bb),256,0,stream>>>((const bf16*)t1, dw_w, dw_b, (bf16*)pgb);
  k_fc2<<<2304,256,0,stream>>>(pgb, xm, Wp2, fc2_b, (float*)d_out);
}

// Round 19
// 770.764 us; speedup vs baseline: 1.1872x; 1.0812x over previous
//
#include <hip/hip_runtime.h>
#include <hip/hip_bf16.h>
#include <math.h>
#include <type_traits>

#define Bb 8
#define Cc 180
#define HWn 9216
#define PD 16
#define CRr 60
#define HID 360
#define H2 720
#define NF 49
#define SPL 9408   /* spectral plane stride in floats: 96*49*2 */
#define CONV_SCALE 0.01f
#define FFT_RES 0.15f
#define EPSLN 1e-5f
#define TWOPI_96 0.06544984694978735f

typedef __hip_bfloat16 bf16;
typedef unsigned short ushort;
typedef __attribute__((ext_vector_type(8))) short s8v;   // 8 bf16 (4 VGPRs) MFMA A/B frag
typedef __attribute__((ext_vector_type(4))) float f4v;   // MFMA C/D frag
struct us4 { ushort x,y,z,w; };

__device__ __forceinline__ float geluf(float x){ return 0.5f*x*(1.0f+erff(x*0.7071067811865476f)); }
__device__ __forceinline__ float sigm(float x){ return 1.0f/(1.0f+expf(-x)); }
__device__ __forceinline__ short f2bf(float f){
  unsigned u = __float_as_uint(f);
  u += 0x7fff + ((u>>16)&1);
  return (short)(u>>16);
}
__device__ __forceinline__ float bf2f(ushort u){ return __uint_as_float(((unsigned)u)<<16); }
__device__ __forceinline__ float wredsum(float v){
#pragma unroll
  for(int m=1;m<64;m<<=1) v += __shfl_xor(v,m,64);
  return v;
}

// ---------------- LN1 + transpose to (B,C,H,W) + fused plane-mean partials ----------------
__global__ void __launch_bounds__(256) k_ln1(const float* __restrict__ x, const float* __restrict__ g,
                      const float* __restrict__ be, float* __restrict__ ximg, float* __restrict__ m1){
  __shared__ float sb[32*Cc];
  int b = blockIdx.x / 288;
  int n0 = (blockIdx.x % 288) * 32;
  int t = threadIdx.x;
  const float* src = x + (size_t)(b*HWn + n0)*Cc;
  for(int i=t;i<32*Cc;i+=256) sb[i]=src[i];
  __syncthreads();
  int w = t>>6, lane = t&63;
  for(int pi=0; pi<8; ++pi){
    int p = w*8+pi;
    float s=0.f, sq=0.f;
    for(int e=lane;e<Cc;e+=64){ float v=sb[p*Cc+e]; s+=v; sq+=v*v; }
    s = wredsum(s); sq = wredsum(sq);
    float mean = s*(1.0f/180.0f);
    float var = sq*(1.0f/180.0f) - mean*mean;
    float rstd = rsqrtf(var + EPSLN);
    for(int e=lane;e<Cc;e+=64){ float v=sb[p*Cc+e]; sb[p*Cc+e] = (v-mean)*rstd*g[e]+be[e]; }
  }
  __syncthreads();
  if(t<Cc){
    float s=0.f;
#pragma unroll 8
    for(int p=0;p<32;p++) s += sb[p*Cc+t];
    atomicAdd(&m1[b*Cc+t], s*(1.0f/9216.0f));
  }
  for(int i=t;i<32*Cc;i+=256){
    int c = i/32, p = i%32;
    ximg[(size_t)(b*Cc+c)*HWn + n0 + p] = sb[p*Cc+c];
  }
}

// ---------------- small: gates, hdn->dk, fft bias ----------------
__global__ void k_small(const float* __restrict__ m1, const float* __restrict__ gate_w,
   const float* __restrict__ gate_b, const float* __restrict__ dwc_w1, const float* __restrict__ dwc_b1,
   const float* __restrict__ dwc_w2, const float* __restrict__ dwc_b2, const float* __restrict__ band_b,
   float* __restrict__ gates, float* __restrict__ dkb, float* __restrict__ biasb){
  int b = threadIdx.x;
  if(b>=Bb) return;
  const float* m = m1 + b*Cc;
  float gv[3];
  for(int k=0;k<3;k++){ float a=gate_b[k]; for(int c=0;c<Cc;c++) a+=m[c]*gate_w[k*Cc+c]; gv[k]=sigm(a);}
  float e0=expf(gv[0]), e1=expf(gv[1]), e2=expf(gv[2]); float inv=1.0f/(e0+e1+e2);
  float g0=e0*inv,g1=e1*inv,g2=e2*inv;
  gates[b*3+0]=g0; gates[b*3+1]=g1; gates[b*3+2]=g2;
  float hd[8];
  for(int j=0;j<8;j++){ float a=dwc_b1[j]; for(int c=0;c<PD;c++) a+=m[c]*dwc_w1[j*PD+c]; hd[j]=geluf(a);}
  for(int i=0;i<144;i++){ float a=dwc_b2[i]; for(int j=0;j<8;j++) a+=hd[j]*dwc_w2[i*8+j]; dkb[b*144+i]=a; }
  for(int d=0;d<Cc;d++) biasb[b*Cc+d] = g0*band_b[0*Cc+d]+g1*band_b[1*Cc+d]+g2*band_b[2*Cc+d];
}

// ------- pack weights to bf16 + DFT twiddle matrices (+ zero m1/gapb accumulators) -------
// ALL MFMA operand matrices packed FRAGMENT-MAJOR (lane-contiguous 1KB per fragment):
//   Wg1, Wg2, Wbk, Wpa, Wp2, and the DFT twiddles Bfx / Tm / Bix.
__global__ void __launch_bounds__(256) k_packw(const float* __restrict__ w1, const float* __restrict__ w2,
    const float* __restrict__ fw1, const float* __restrict__ fw2, const float* __restrict__ aw,
    const float* __restrict__ bw,
    ushort* __restrict__ Wg1, ushort* __restrict__ Wg2, ushort* __restrict__ Wp1,
    ushort* __restrict__ Wp2, ushort* __restrict__ Wpa, ushort* __restrict__ Wbk,
    ushort* __restrict__ Bfx, ushort* __restrict__ Tm, ushort* __restrict__ Bix,
    float* __restrict__ m1z, float* __restrict__ gapz){
  int t = blockIdx.x*256 + threadIdx.x;
  if(t < Bb*Cc){ m1z[t]=0.f; gapz[t]=0.f; }
  // Wg1 (conv1, ct=0, NCHUNK=6): f = (tap*6+ch)*4+ts ; 216 frags x 512 = 110592
  if(t < 110592){
    int q=t&7; int lane=(t>>3)&63; int f=t>>9;
    int kq=lane>>4, lr=lane&15;
    int ts=f&3; int rest=f>>2; int ch=rest%6; int tap=rest/6;
    int co=ts*16+lr, ci=ch*32+kq*8+q;
    float v=(co<CRr&&ci<Cc)? w1[((size_t)(co*Cc+ci))*9+tap]:0.f;
    Wg1[t]=(ushort)f2bf(v);
  }
  // Wg2 (conv2, 3 ct, NCHUNK=2): f = ((ct*9+tap)*2+ch)*4+ts ; 216 frags x 512 = 110592
  if(t < 110592){
    int q=t&7; int lane=(t>>3)&63; int f=t>>9;
    int kq=lane>>4, lr=lane&15;
    int ts=f&3; int rest=f>>2; int ch=rest&1; rest>>=1; int tap=rest%9; int ct=rest/9;
    int co=ct*64+ts*16+lr, ci=ch*32+kq*8+q;
    float v=(co<Cc&&ci<CRr)? w2[((size_t)(co*CRr+ci))*9+tap]:0.f;
    Wg2[t]=(ushort)f2bf(v);
  }
  if(t < 768*192){
    int j=t/192, k=t%192;
    Wp1[t] = (ushort)f2bf((j<H2 && k<Cc)? fw1[(size_t)j*Cc+k] : 0.f);
  }
  // Wp2 fragment-major: t = (ct*12+k6)*512 + lane*8 + q ; d=ct*16+lr, c=kq*8+k6*32+q
  if(t < 192*384){
    int q = t&7; int rest = t>>3;
    int lane = rest&63; rest >>= 6;
    int kq = lane>>4, lr = lane&15;
    int k6 = rest%12; int ct = rest/12;
    int d = ct*16+lr, c = kq*8 + k6*32 + q;
    Wp2[t] = (ushort)f2bf((d<Cc && c<HID)? fw2[(size_t)d*HID+c] : 0.f);
  }
  // Wpa fragment-major: t = ((jt*6+k6)*4+kq)*128 + lr*8 + q ; d=jt*16+lr, c=kq*8+k6*32+q
  if(t < 192*192){
    int q = t&7; int rest = t>>3;
    int lr = rest&15; rest >>= 4;
    int kq = rest&3; rest >>= 2;
    int k6 = rest%6; int jt = rest/6;
    int d = jt*16+lr, c = kq*8 + k6*32 + q;
    Wpa[t] = (ushort)f2bf((d<Cc && c<Cc)? aw[(size_t)d*Cc+c] : 0.f);
  }
  // Wbk fragment-major: t = (((k*12+ts)*6+k6)*4+kq)*128 + lr*8 + q ; d=ts*16+lr, c=kq*8+k6*32+q
  if(t < 3*192*192){
    int q = t&7; int rest = t>>3;
    int lr = rest&15; rest >>= 4;
    int kq = rest&3; rest >>= 2;
    int k6 = rest%6; rest /= 6;
    int ts = rest%12; int k = rest/12;
    int d = ts*16+lr, c = kq*8 + k6*32 + q;
    Wbk[t] = (ushort)f2bf((d<Cc && c<Cc)? bw[((size_t)k*Cc + d)*Cc + c] : 0.f);
  }
  // Bfx fragment-major: f = nt*3+ks (21 frags x 512 = 10752); n=nt*16+lr, k=kq*8+ks*32+q
  if(t < 112*96){
    int q=t&7; int lane=(t>>3)&63; int f=t>>9;
    int kq=lane>>4, lr=lane&15;
    int ks=f%3, nt=f/3;
    int n = nt*16+lr, k = kq*8 + ks*32 + q;
    float v=0.f;
    if(n<98){
      int kx=n>>1; int m=(k*kx)%96; float th=(float)m*TWOPI_96;
      v = ((n&1)? -sinf(th) : cosf(th)) * (1.0f/96.0f);
    }
    Bfx[t] = (ushort)f2bf(v);
  }
  // Tm fragment-major: f = mt*6+ks (36 frags x 512 = 18432); r=mt*16+lr, k=kq*8+ks*32+q
  if(t < 96*192){
    int q=t&7; int lane=(t>>3)&63; int f=t>>9;
    int kq=lane>>4, lr=lane&15;
    int ks=f%6, mt=f/6;
    int r = mt*16+lr, k = kq*8 + ks*32 + q;
    int c=k>>1; int m=(r*c)%96; float th=(float)m*TWOPI_96;
    float v = (k&1)? sinf(th) : cosf(th);
    Tm[t] = (ushort)f2bf(v);
  }
  // Bix fragment-major: f = nt*4+ks (24 frags x 512 = 12288); n=nt*16+lr, k=kq*8+ks*32+q
  if(t < 96*128){
    int q=t&7; int lane=(t>>3)&63; int f=t>>9;
    int kq=lane>>4, lr=lane&15;
    int ks=f%4, nt=f/4;
    int n = nt*16+lr, k = kq*8 + ks*32 + q;
    float v=0.f;
    if(k<98){
      int kx=k>>1; float wgt=(kx==0||kx==48)?1.0f:2.0f;
      int m=(n*kx)%96; float th=(float)m*TWOPI_96;
      v = ((k&1)? -wgt*sinf(th) : wgt*cosf(th)) * (1.0f/96.0f);
    }
    Bix[t] = (ushort)f2bf(v);
  }
}

// ------- pack plk + per-batch dynamic depthwise into Wdk[b][co][13ky][7kxp][2tl*16ci] bf16 -------
__global__ void __launch_bounds__(256) k_packplk(const float* __restrict__ plk,
    const float* __restrict__ dkb, ushort* __restrict__ Wdk){
  int t = blockIdx.x*256 + threadIdx.x;
  if(t >= Bb*PD*13*7*32) return;
  int k = t & 31; int rest = t >> 5;
  int kxp = rest % 7; rest /= 7;
  int ky = rest % 13; rest /= 13;
  int co = rest % PD; int b = rest / PD;
  int tl = k >> 4, ci = k & 15;
  int kx = kxp*2 + tl;
  float v = 0.f;
  if(kx < 13){
    v = plk[((size_t)(co*PD+ci)*13 + ky)*13 + kx];
    if(ci==co && ky>=5 && ky<8 && kx>=5 && kx<8)
      v += dkb[b*144 + co*9 + (ky-5)*3 + (kx-5)];
  }
  Wdk[t] = (ushort)f2bf(v);
}

// ---------------- fused forward 2D rDFT (per plane), MFMA, 8 waves; twiddles fragment-major ----------------
__global__ void __launch_bounds__(512) k_fft_fwd(const float* __restrict__ ximg,
    const ushort* __restrict__ Bfx, const ushort* __restrict__ Tm, float* __restrict__ S){
  __shared__ __align__(16) short Asi[96*104];
  __shared__ __align__(16) short Bv[112*200];
  int bc = blockIdx.x; int t = threadIdx.x;
  int w=t>>6, lane=t&63, kq=lane>>4, lr=lane&15;
  const float* src = ximg + (size_t)bc*HWn;
  for(int i=t;i<1152;i+=512){
    int y=i/12, seg=i%12;
    float4 v0 = *(const float4*)(src + y*96 + seg*8);
    float4 v1 = *(const float4*)(src + y*96 + seg*8 + 4);
    s8v pk;
    pk[0]=f2bf(v0.x); pk[1]=f2bf(v0.y); pk[2]=f2bf(v0.z); pk[3]=f2bf(v0.w);
    pk[4]=f2bf(v1.x); pk[5]=f2bf(v1.y); pk[6]=f2bf(v1.z); pk[7]=f2bf(v1.w);
    *(s8v*)&Asi[y*104+seg*8] = pk;
  }
  __syncthreads();
  for(int tile=w; tile<42; tile+=8){
    int mt=tile/7, nt=tile%7;
    f4v acc={};
#pragma unroll
    for(int ks=0;ks<3;ks++){
      s8v af = *(const s8v*)&Asi[(mt*16+lr)*104 + kq*8 + ks*32];
      s8v bf = *(const s8v*)&Bfx[((size_t)(nt*3+ks))*512 + lane*8];
      acc = __builtin_amdgcn_mfma_f32_16x16x32_bf16(af,bf,acc,0,0,0);
    }
    int n = nt*16+lr;
    float sgn = (n&1)? -1.f : 1.f;
#pragma unroll
    for(int reg=0;reg<4;reg++){
      int y = mt*16+kq*4+reg;
      float v = acc[reg];
      float p = __shfl_xor(v,1);
      unsigned pack = ((unsigned)(ushort)f2bf(sgn*p)<<16) | (ushort)(unsigned short)f2bf(v);
      *(unsigned*)&Bv[n*200 + 2*y] = pack;
    }
  }
  __syncthreads();
  float* dst = S + (size_t)bc*SPL;
  for(int tile=w; tile<42; tile+=8){
    int mt=tile/7, nt=tile%7;
    f4v acc={};
#pragma unroll
    for(int ks=0;ks<6;ks++){
      s8v af = *(const s8v*)&Tm[((size_t)(mt*6+ks))*512 + lane*8];
      s8v bf = *(const s8v*)&Bv[(nt*16+lr)*200 + kq*8 + ks*32];
      acc = __builtin_amdgcn_mfma_f32_16x16x32_bf16(af,bf,acc,0,0,0);
    }
    int n = nt*16+lr;
    if(n<98){
#pragma unroll
      for(int reg=0;reg<4;reg++){
        int ky = mt*16+kq*4+reg;
        dst[ky*98 + n] = acc[reg];
      }
    }
  }
}

// ---------------- fused inverse 2D rDFT + combine (per plane), MFMA, 8 waves; twiddles fragment-major ----------------
__global__ void __launch_bounds__(512) k_fft_inv(float* __restrict__ S, const float* __restrict__ ximg,
    const float* __restrict__ biasb, const ushort* __restrict__ Tm, const ushort* __restrict__ Bix){
  __shared__ __align__(16) short Bv[112*200];
  __shared__ __align__(16) short T2s[96*136];
  int bd = blockIdx.x; int t=threadIdx.x;
  int w=t>>6, lane=t&63, kq=lane>>4, lr=lane&15;
  int b = bd/Cc, d = bd%Cc;
  float* pl = S + (size_t)bd*SPL;
  for(int i=t;i<1400;i+=512) ((unsigned*)&Bv[98*200])[i] = 0u;
  for(int i=t;i<1152;i+=512){ int y=i/12, c=i%12; *(unsigned*)&T2s[y*136+112+c*2] = 0u; }
  for(int i2=t;i2<4704;i2+=512){
    int idx = i2*2;
    float2 v = *(const float2*)(pl + idx);
    int ky = idx/98, n = idx%98;     // n even
    unsigned pack0 = ((unsigned)(ushort)f2bf(-v.y)<<16) | (ushort)(unsigned short)f2bf(v.x);
    unsigned pack1 = ((unsigned)(ushort)f2bf( v.x)<<16) | (ushort)(unsigned short)f2bf(v.y);
    *(unsigned*)&Bv[n*200 + 2*ky]     = pack0;
    *(unsigned*)&Bv[(n+1)*200 + 2*ky] = pack1;
  }
  __syncthreads();
  for(int tile=w; tile<42; tile+=8){
    int mt=tile/7, nt=tile%7;
    f4v acc={};
#pragma unroll
    for(int ks=0;ks<6;ks++){
      s8v af = *(const s8v*)&Tm[((size_t)(mt*6+ks))*512 + lane*8];
      s8v bf = *(const s8v*)&Bv[(nt*16+lr)*200 + kq*8 + ks*32];
      acc = __builtin_amdgcn_mfma_f32_16x16x32_bf16(af,bf,acc,0,0,0);
    }
    int n = nt*16+lr;
#pragma unroll
    for(int reg=0;reg<4;reg++){
      int y = mt*16+kq*4+reg;
      T2s[y*136 + n] = f2bf(acc[reg]);
    }
  }
  __syncthreads();
  float bias = biasb[b*Cc+d];
  const float* xs = ximg + (size_t)bd*HWn;
  ushort* po = (ushort*)pl;
  for(int tile=w; tile<36; tile+=8){
    int mt=tile/6, nt=tile%6;
    f4v acc={};
#pragma unroll
    for(int ks=0;ks<4;ks++){
      s8v af = *(const s8v*)&T2s[(mt*16+lr)*136 + kq*8 + ks*32];
      s8v bf = *(const s8v*)&Bix[((size_t)(nt*4+ks))*512 + lane*8];
      acc = __builtin_amdgcn_mfma_f32_16x16x32_bf16(af,bf,acc,0,0,0);
    }
    int xx = nt*16+lr;
#pragma unroll
    for(int reg=0;reg<4;reg++){
      int y = mt*16+kq*4+reg;
      int o = y*96+xx;
      po[o] = (ushort)f2bf(xs[o] + FFT_RES*(acc[reg] + bias));
    }
  }
}

// ---------------- band channel mix as MFMA GEMM, IN-PLACE, 8 waves, Wbk fragment-major ----------------
__global__ void __launch_bounds__(512) k_bandmixm(float* __restrict__ S, const ushort* __restrict__ Wbk,
                          const float* __restrict__ gates){
  __shared__ __align__(16) short Bs[64*200];
  int f2base = blockIdx.x*64;
  int b = blockIdx.y;
  int t = threadIdx.x;
  int w=t>>6, lane=t&63, kq=lane>>4, lr=lane&15;
  int wr = w&3, chh = w>>2;
  for(int i=t;i<8*192;i+=512){
    int rblk=i&7, kk=i>>3;
    int r0=rblk*8;
    if(kk<Cc){
      const float* src = S + (size_t)(b*Cc+kk)*SPL + f2base + r0;
      float4 v0 = *(const float4*)src;
      float4 v1 = *(const float4*)(src+4);
      Bs[(r0+0)*200+kk]=f2bf(v0.x); Bs[(r0+1)*200+kk]=f2bf(v0.y);
      Bs[(r0+2)*200+kk]=f2bf(v0.z); Bs[(r0+3)*200+kk]=f2bf(v0.w);
      Bs[(r0+4)*200+kk]=f2bf(v1.x); Bs[(r0+5)*200+kk]=f2bf(v1.y);
      Bs[(r0+6)*200+kk]=f2bf(v1.z); Bs[(r0+7)*200+kk]=f2bf(v1.w);
    } else {
#pragma unroll
      for(int q=0;q<8;q++) Bs[(r0+q)*200+kk]=0;
    }
  }
  unsigned bmask;
  {
    int col = f2base + lane;
    int ky = col/98, n = col%98, kx = n>>1;
    float yy = -1.0f + 2.0f*(float)ky/95.0f;
    float xxf = (float)kx/48.0f;
    float rr = sqrtf(yy*yy+xxf*xxf);
    int k = (rr<=0.25f)?0:((rr<=0.6f)?1:2);
    unsigned m = 1u<<k;
#pragma unroll
    for(int s=1;s<64;s<<=1) m |= __shfl_xor(m,s);
    bmask = m;
  }
  int kb[4]; float gv[4];
#pragma unroll
  for(int reg=0;reg<4;reg++){
    int col = f2base + wr*16 + kq*4 + reg;
    int ky = col/98, n = col%98, kx = n>>1;
    float yy = -1.0f + 2.0f*(float)ky/95.0f;
    float xxf = (float)kx/48.0f;
    float rr = sqrtf(yy*yy+xxf*xxf);
    kb[reg] = (rr<=0.25f)?0:((rr<=0.6f)?1:2);
    gv[reg] = gates[b*3+kb[reg]];
  }
  __syncthreads();
  s8v af[6];
#pragma unroll
  for(int k6=0;k6<6;k6++) af[k6] = *(const s8v*)&Bs[(wr*16+lr)*200 + kq*8 + k6*32];
  float res[6][4];
  for(int k=0;k<3;k++){
    if(!(bmask&(1u<<k))) continue;
    for(int j=0;j<6;j++){
      int ts = chh*6 + j;
      f4v acc={};
#pragma unroll
      for(int k6=0;k6<6;k6++){
        s8v wf = *(const s8v*)&Wbk[((size_t)((k*12+ts)*6 + k6))*512 + lane*8];
        acc = __builtin_amdgcn_mfma_f32_16x16x32_bf16(af[k6],wf,acc,0,0,0);
      }
#pragma unroll
      for(int reg=0;reg<4;reg++) if(kb[reg]==k) res[j][reg]=gv[reg]*acc[reg];
    }
  }
#pragma unroll
  for(int j=0;j<6;j++){
    int d = (chh*6+j)*16+lr;
    if(d<Cc){
      float4 o; o.x=res[j][0]; o.y=res[j][1]; o.z=res[j][2]; o.w=res[j][3];
      *(float4*)(S + (size_t)(b*Cc+d)*SPL + f2base + wr*16 + kq*4) = o;
    }
  }
}

// ---------------- CAB 3x3 conv as implicit-GEMM MFMA, bf16 in/out,
//                  Wg FRAGMENT-MAJOR (lane-contiguous weight loads) ----------------
template<int NW, int CIN, int KPAD, int NCHUNK, bool ACT, bool OUTBF>
__global__ void __launch_bounds__(NW*64) k_cab(const ushort* __restrict__ xin, const ushort* __restrict__ Wg,
    const float* __restrict__ bias, ushort* __restrict__ out, int COUT, int istride,
    float* __restrict__ gapp){
  constexpr int NT = NW*64;
  constexpr int STILES = 12/NW;
  __shared__ short As[4*98*36];
  int y0 = blockIdx.x*2;
  int ct = blockIdx.y;
  int b  = blockIdx.z;
  int t = threadIdx.x;
  int w = t>>6, lane = t&63, kq = lane>>4, lr = lane&15;
  f4v acc[STILES][4] = {};
  for(int ch=0; ch<NCHUNK; ++ch){
    int ci0 = ch*32;
    __syncthreads();
    for(int u=t; u<4*12*32; u+=NT){
      int ci = u&31; int rest = u>>5; int seg = rest%12; int row = rest/12;
      int gy = y0 - 1 + row; int cig = ci0+ci;
      s8v v = {};
      if((unsigned)gy<96u && cig<CIN)
        v = *(const s8v*)&xin[(size_t)(b*CIN+cig)*istride + gy*96 + seg*8];
      int base = (row*98 + seg*8 + 1)*36 + ci;
#pragma unroll
      for(int q=0;q<8;q++) As[base + q*36] = v[q];
    }
    for(int u=t; u<4*2*32; u+=NT){
      int ci=u&31; int rest=u>>5; int e=rest&1; int row=rest>>1;
      As[(row*98 + (e?97:0))*36 + ci] = 0;
    }
    __syncthreads();
#pragma unroll
    for(int tap=0; tap<9; ++tap){
      int ky = tap/3, kx = tap%3;
      s8v bfr[4];
#pragma unroll
      for(int ts=0;ts<4;ts++)
        bfr[ts] = *(const s8v*)&Wg[((size_t)(((ct*9+tap)*NCHUNK+ch)*4+ts))*512 + lane*8];
#pragma unroll
      for(int s=0;s<STILES;s++){
        int mt = w + NW*s;
        int orow = mt/6, px = (mt%6)*16 + lr;
        s8v af = *(const s8v*)&As[((orow+ky)*98 + px + kx)*36 + kq*8];
#pragma unroll
        for(int ts=0;ts<4;ts++)
          acc[s][ts] = __builtin_amdgcn_mfma_f32_16x16x32_bf16(af, bfr[ts], acc[s][ts], 0,0,0);
      }
    }
  }
  if(OUTBF){
    __syncthreads();
    short* cT = As;
#pragma unroll
    for(int ts=0;ts<4;ts++){
      int cog = ct*64 + ts*16 + lr;
      float bb = (cog<COUT)? bias[cog] : 0.f;
#pragma unroll
      for(int s=0;s<STILES;s++){
        int mt = w + NW*s;
#pragma unroll
        for(int reg=0;reg<4;reg++){
          int px = mt*16 + kq*4 + reg;
          float v = acc[s][ts][reg] + bb;
          if(ACT) v = geluf(v);
          cT[(ts*16+lr)*200 + px] = f2bf(v);
        }
      }
    }
    __syncthreads();
    for(int i=t;i<64*24;i+=NT){
      int co=i/24, seg=i%24;
      int cog = ct*64+co;
      if(cog<COUT)
        *(s8v*)&out[(size_t)(b*COUT+cog)*HWn + y0*96 + seg*8] = *(const s8v*)&cT[co*200+seg*8];
    }
  } else {
    float* cF = (float*)As;
    for(int h=0;h<2;h++){
      __syncthreads();
#pragma unroll
      for(int tt=0;tt<2;tt++){
        int ts = 2*h+tt;
        int cog = ct*64 + ts*16 + lr;
        float bb = (cog<COUT)? bias[cog] : 0.f;
#pragma unroll
        for(int s=0;s<STILES;s++){
          int mt = w + NW*s;
#pragma unroll
          for(int reg=0;reg<4;reg++){
            int px = mt*16 + kq*4 + reg;
            cF[(tt*16+lr)*200 + px] = acc[s][ts][reg] + bb;
          }
        }
      }
      __syncthreads();
      for(int i=t;i<32*24;i+=NT){
        int co=i/24, seg=i%24;
        int cog = ct*64 + h*32 + co;
        if(cog<COUT){
          s8v pk;
#pragma unroll
          for(int q=0;q<8;q++) pk[q] = f2bf(cF[co*200+seg*8+q]);
          *(s8v*)&out[(size_t)(b*COUT+cog)*HWn + y0*96 + seg*8] = pk;
        }
      }
      if(gapp){
        for(int row=w; row<32; row+=NW){
          int cog = ct*64 + h*32 + row;
          float s=0.f;
#pragma unroll
          for(int px=lane;px<192;px+=64) s += cF[row*200+px];
          s = wredsum(s);
          if(lane==0 && cog<COUT) atomicAdd(&gapp[(size_t)b*COUT+cog], s*(1.0f/9216.0f));
        }
      }
    }
  }
}

// ---------------- ECA ----------------
__global__ void k_eca(const float* __restrict__ gap, const float* __restrict__ ew, float* __restrict__ s){
  int i = blockIdx.x*blockDim.x + threadIdx.x;
  if(i>=Bb*Cc) return;
  int b=i/Cc, c=i%Cc;
  float z=0.f;
  for(int j=0;j<5;j++){ int cc=c-2+j; if(cc>=0&&cc<Cc) z+=gap[b*Cc+cc]*ew[j]; }
  s[i]=sigm(z);
}

// ------- plk 13x13 + fused dynamic dw3x3 as implicit-GEMM MFMA (tap-pair K=32), 6 waves -------
__global__ void __launch_bounds__(384) k_plkm(const float* __restrict__ ximg,
    const ushort* __restrict__ Wdk, float* __restrict__ attn){
  __shared__ short As[15*109*20];
  int y0 = blockIdx.x*3;
  int b  = blockIdx.y;
  int t = threadIdx.x;
  int w = t>>6, lane = t&63, kq = lane>>4, lr = lane&15;
  for(int i=t;i<PD*15*109;i+=384){
    int ci = i/(15*109); int rem = i%(15*109);
    int row = rem/109, pxh = rem%109;
    int gy = y0 + row - 6, gx = pxh - 6;
    short sv = 0;
    if((unsigned)gy<96u && (unsigned)gx<96u)
      sv = f2bf(ximg[(size_t)(b*Cc+ci)*HWn + gy*96 + gx]);
    As[(row*109+pxh)*20 + ci] = sv;
  }
  __syncthreads();
  f4v acc[3] = {};
  const ushort* wb = Wdk + ((size_t)(b*PD+lr)*13)*7*32 + kq*8;
  for(int ky=0;ky<13;ky++){
#pragma unroll
    for(int kxp=0;kxp<7;kxp++){
      s8v bfr = *(const s8v*)(wb + (ky*7+kxp)*32);
#pragma unroll
      for(int ti=0;ti<3;ti++){
        int mt = w + 6*ti;
        int yo = mt/6, o = (mt%6)*16;
        s8v af = *(const s8v*)&As[((yo+ky)*109 + o + lr + 2*kxp + (kq>>1))*20 + (kq&1)*8];
        acc[ti] = __builtin_amdgcn_mfma_f32_16x16x32_bf16(af, bfr, acc[ti], 0,0,0);
      }
    }
  }
#pragma unroll
  for(int ti=0;ti<3;ti++){
    int mt = w + 6*ti;
    int yo = mt/6, o = (mt%6)*16 + kq*4;
    float4 ov; ov.x=acc[ti][0]; ov.y=acc[ti][1]; ov.z=acc[ti][2]; ov.w=acc[ti][3];
    *(float4*)&attn[(size_t)(b*PD+lr)*HWn + (y0+yo)*96 + o] = ov;
  }
}

// ---------------- aggr MFMA GEMM, 8 waves, Wpa fragment-major; + residual + LN2 ----------------
__global__ void __launch_bounds__(512) k_aggrm(const float* __restrict__ x, const float* __restrict__ attn,
   const float* __restrict__ ximg, const ushort* __restrict__ ycab, const ushort* __restrict__ Wpa,
   const float* __restrict__ aggb, const float* __restrict__ svec,
   const float* __restrict__ g2, const float* __restrict__ b2,
   float* __restrict__ xm, ushort* __restrict__ xn2){
  __shared__ __align__(16) float smem[64*188];
  short* As = (short*)smem;
  float* cF = smem;
  int rt = blockIdx.x;
  int t = threadIdx.x;
  int w = t>>6, lane = t&63, kq = lane>>4, lr = lane&15;
  int grow0 = rt*64; int b = grow0/HWn; int n0 = grow0%HWn;
  for(int i=t;i<8*192;i+=512){
    int rblk=i&7, kk=i>>3;
    int r0=rblk*8;
    if(kk<Cc){
      const float* src = (kk<PD)? attn + (size_t)(b*PD+kk)*HWn + n0 + r0
                                : ximg + (size_t)(b*Cc+kk)*HWn + n0 + r0;
      float4 v0 = *(const float4*)src;
      float4 v1 = *(const float4*)(src+4);
      As[(r0+0)*200+kk]=f2bf(v0.x); As[(r0+1)*200+kk]=f2bf(v0.y);
      As[(r0+2)*200+kk]=f2bf(v0.z); As[(r0+3)*200+kk]=f2bf(v0.w);
      As[(r0+4)*200+kk]=f2bf(v1.x); As[(r0+5)*200+kk]=f2bf(v1.y);
      As[(r0+6)*200+kk]=f2bf(v1.z); As[(r0+7)*200+kk]=f2bf(v1.w);
    } else {
#pragma unroll
      for(int q=0;q<8;q++) As[(r0+q)*200+kk]=0;
    }
  }
  __syncthreads();
  int wr = w&3, ch = w>>2;
  s8v af[6];
  int arow=(wr*16+lr)*200 + kq*8;
#pragma unroll
  for(int k6=0;k6<6;k6++) af[k6] = *(const s8v*)&As[arow + k6*32];
  f4v acc[6]={};
#pragma unroll
  for(int j=0;j<6;j++){
    int jt = ch*6+j;
#pragma unroll
    for(int k6=0;k6<6;k6++){
      s8v wf = *(const s8v*)&Wpa[((size_t)(jt*6 + k6))*512 + lane*8];
      acc[j]=__builtin_amdgcn_mfma_f32_16x16x32_bf16(af[k6],wf,acc[j],0,0,0);
    }
  }
  __syncthreads();
#pragma unroll
  for(int j=0;j<6;j++){
    int jc = (ch*6+j)*16 + lr;
    if(jc<Cc){
      float bb = aggb[jc];
      float sv = CONV_SCALE*svec[b*Cc+jc];
      const ushort* yrow = ycab + (size_t)(b*Cc+jc)*HWn + n0;
#pragma unroll
      for(int reg=0;reg<4;reg++){
        int m = wr*16 + kq*4 + reg;
        cF[m*188+jc] = acc[j][reg] + bb + sv*bf2f(yrow[m]);
      }
    }
  }
  __syncthreads();
  for(int r=0;r<8;r++){
    int m = w*8 + r;
    size_t baseo = (size_t)(grow0+m)*Cc;
    float vbuf[3];
    float s=0.f, sq=0.f;
#pragma unroll
    for(int it=0;it<3;it++){
      int e = lane + it*64;
      float v = (e<Cc)? cF[m*188+e] + x[baseo+e] : 0.f;
      vbuf[it]=v; s+=v; sq+=v*v;
    }
    s=wredsum(s); sq=wredsum(sq);
    float mean = s*(1.0f/180.0f);
    float var = sq*(1.0f/180.0f) - mean*mean;
    float rstd = rsqrtf(var + EPSLN);
    ushort* orow = xn2 + (size_t)(grow0+m)*192;
#pragma unroll
    for(int it=0;it<3;it++){
      int e = lane + it*64;
      if(e<Cc){
        float v = vbuf[it];
        xm[baseo+e] = v;
        orow[e] = (ushort)f2bf((v-mean)*rstd*g2[e]+b2[e]);
      } else {
        orow[e] = 0;
      }
    }
  }
}

// -------- fc1 MFMA: W-tile staged to LDS via coalesced s8v copies --------
__global__ void __launch_bounds__(256) k_fc1(const ushort* __restrict__ xn2,
    const ushort* __restrict__ Wp, const float* __restrict__ fb, ushort* __restrict__ t1){
  __shared__ __align__(16) short Ws[64*200];
  int rt = blockIdx.x;
  int t = threadIdx.x;
  int w = t>>6, lane = t&63, kq = lane>>4, lr = lane&15;
  int grow0 = rt*64;
  int bb_ = grow0/HWn, n0 = grow0%HWn;
  s8v af[6];
  const ushort* arow = xn2 + (size_t)(grow0 + w*16 + lr)*192 + kq*8;
#pragma unroll
  for(int k6=0;k6<6;k6++) af[k6] = *(const s8v*)(arow + k6*32);
  int mcol = n0 + w*16 + kq*4;
  for(int ct=0; ct<12; ++ct){
    __syncthreads();
    const s8v* src = (const s8v*)(Wp + (size_t)ct*64*192);
#pragma unroll
    for(int q=0;q<6;q++){
      int i = t + q*256;
      int j = i/24, seg = i%24;
      *(s8v*)&Ws[j*200 + seg*8] = src[i];
    }
    __syncthreads();
    f4v acc[4]={};
#pragma unroll
    for(int k6=0;k6<6;k6++){
#pragma unroll
      for(int ts=0;ts<4;ts++){
        s8v wf = *(const s8v*)&Ws[(ts*16+lr)*200 + kq*8 + k6*32];
        acc[ts]=__builtin_amdgcn_mfma_f32_16x16x32_bf16(af[k6],wf,acc[ts],0,0,0);
      }
    }
#pragma unroll
    for(int ts=0;ts<4;ts++){
      int jc = ct*64 + ts*16 + lr;
      if(jc<H2){
        float bb = fb[jc];
        us4 pk;
        pk.x=(ushort)f2bf(acc[ts][0]+bb); pk.y=(ushort)f2bf(acc[ts][1]+bb);
        pk.z=(ushort)f2bf(acc[ts][2]+bb); pk.w=(ushort)f2bf(acc[ts][3]+bb);
        *(us4*)&t1[((size_t)(bb_*H2+jc))*HWn + mcol] = pk;
      }
    }
  }
}

// ---------------- depthwise 3x3 on t1 + GLU -> pg (B,360,HW) bf16 ----------------
__global__ void __launch_bounds__(256) k_dwglu(const bf16* __restrict__ t1, const float* __restrict__ dww,
    const float* __restrict__ dwb, bf16* __restrict__ pg){
  __shared__ float ta[34*34];
  __shared__ float tg[34*34];
  int tile_id=blockIdx.x; int c=blockIdx.y; int b=blockIdx.z;
  int ty0=(tile_id/3)*32, tx0=(tile_id%3)*32;
  int t=threadIdx.x;
  int px0=(t%16)*2, py0=(t/16)*2;
  for(int i=t;i<34*34;i+=256){
    int ly=i/34, lx=i%34; int gy=ty0+ly-1, gx=tx0+lx-1;
    bool ok=((unsigned)gy<96u&&(unsigned)gx<96u);
    ta[i]= ok? __bfloat162float(t1[((size_t)(b*H2+c)*96+gy)*96+gx]) :0.f;
    tg[i]= ok? __bfloat162float(t1[((size_t)(b*H2+c+HID)*96+gy)*96+gx]) :0.f;
  }
  __syncthreads();
  float wp[9],wg[9];
#pragma unroll
  for(int i=0;i<9;i++){ wp[i]=dww[c*9+i]; wg[i]=dww[(c+HID)*9+i]; }
  float bp=dwb[c], bg=dwb[c+HID];
#pragma unroll
  for(int oy=0;oy<2;oy++)
#pragma unroll
    for(int ox=0;ox<2;ox++){
      float p=bp,g=bg;
#pragma unroll
      for(int ky=0;ky<3;ky++)
#pragma unroll
        for(int kx=0;kx<3;kx++){
          p+=wp[ky*3+kx]*ta[(py0+oy+ky)*34+px0+ox+kx];
          g+=wg[ky*3+kx]*tg[(py0+oy+ky)*34+px0+ox+kx];
        }
      float val = p * g * sigm(g);
      pg[((size_t)(b*HID+c)*96 + ty0+py0+oy)*96 + tx0+px0+ox] = __float2bfloat16(val);
    }
}

// ---------------- fc2 MFMA + residual -> out (B,N,C); BM=32, XOR-swizzled A staging,
//                  Wp2 FRAGMENT-MAJOR (lane-contiguous weight loads) ----------------
__global__ void __launch_bounds__(256) k_fc2(const ushort* __restrict__ pg, const float* __restrict__ xm,
    const ushort* __restrict__ Wp, const float* __restrict__ fb, float* __restrict__ out){
  __shared__ __align__(16) short As[32*392];
  float* cF = (float*)As;
  int rt = blockIdx.x;
  int t = threadIdx.x;
  int w = t>>6, lane = t&63, kq = lane>>4, lr = lane&15;
  int grow0 = rt*32; int b = grow0/HWn; int n0 = grow0%HWn;
  for(int i=t;i<4*HID;i+=256){
    int rblk = i&3; int kc = i>>2;
    int r0 = rblk*8;
    s8v v = *(const s8v*)&pg[((size_t)(b*HID+kc))*HWn + n0 + r0];
    int kcs = kc ^ (rblk<<3);
#pragma unroll
    for(int q=0;q<8;q++) As[(r0+q)*392 + kcs] = v[q];
  }
  for(int i=t;i<32*24;i+=256){
    int r = i/24, kc = 360 + i%24;
    As[r*392 + (kc ^ ((r>>3)<<3))] = 0;
  }
  __syncthreads();
  int mt = w&1;
  int row = mt*16 + lr;
  int rb = row>>3;
  s8v af[12];
#pragma unroll
  for(int k6=0;k6<12;k6++)
    af[k6] = *(const s8v*)&As[row*392 + ((kq ^ rb)<<3) + k6*32];
  f4v acc[6]={};
#pragma unroll
  for(int j=0;j<6;j++){
    int ct = (w>>1) + 2*j;
#pragma unroll
    for(int k6=0;k6<12;k6++){
      s8v wf = *(const s8v*)&Wp[(size_t)(ct*12 + k6)*512 + lane*8];
      acc[j]=__builtin_amdgcn_mfma_f32_16x16x32_bf16(af[k6],wf,acc[j],0,0,0);
    }
  }
  __syncthreads();
#pragma unroll
  for(int j=0;j<6;j++){
    int ct = (w>>1) + 2*j;
    int jc = ct*16 + lr;
    if(jc<Cc){
      float bb = fb[jc];
#pragma unroll
      for(int reg=0;reg<4;reg++){
        int m = mt*16 + kq*4 + reg;
        cF[m*Cc + jc] = acc[j][reg] + bb;
      }
    }
  }
  __syncthreads();
  size_t base = (size_t)grow0*Cc;
  for(int i=t;i<32*Cc;i+=256){
    out[base+i] = xm[base+i] + cF[i];
  }
}

extern "C" void kernel_launch(void* const* d_in, const int* in_sizes, int n_in,
                              void* d_out, int out_size, void* d_ws, size_t ws_size,
                              hipStream_t stream){
  (void)in_sizes; (void)n_in; (void)out_size; (void)ws_size;
  const float* x     = (const float*)d_in[0];
  const float* ln1_g = (const float*)d_in[3];
  const float* ln1_b = (const float*)d_in[4];
  const float* band_w= (const float*)d_in[5];
  const float* band_b= (const float*)d_in[6];
  const float* gate_w= (const float*)d_in[7];
  const float* gate_b= (const float*)d_in[8];
  const float* cab_w1= (const float*)d_in[9];
  const float* cab_b1= (const float*)d_in[10];
  const float* cab_w2= (const float*)d_in[11];
  const float* cab_b2= (const float*)d_in[12];
  const float* eca_w = (const float*)d_in[13];
  const float* plkw  = (const float*)d_in[14];
  const float* dwc_w1= (const float*)d_in[15];
  const float* dwc_b1= (const float*)d_in[16];
  const float* dwc_w2= (const float*)d_in[17];
  const float* dwc_b2= (const float*)d_in[18];
  const float* aggr_w= (const float*)d_in[19];
  const float* aggr_b= (const float*)d_in[20];
  const float* ln2_g = (const float*)d_in[21];
  const float* ln2_b = (const float*)d_in[22];
  const float* fc1_w = (const float*)d_in[23];
  const float* fc1_b = (const float*)d_in[24];
  const float* dw_w  = (const float*)d_in[25];
  const float* dw_b  = (const float*)d_in[26];
  const float* fc2_w = (const float*)d_in[27];
  const float* fc2_b = (const float*)d_in[28];

  float* ws = (float*)d_ws;
  float* xm   = ws;                      // 13,271,040
  float* m1   = ws + 13271040;
  float* gates= ws + 13272480;
  float* dkb  = ws + 13272512;
  float* biasb= ws + 13273664;
  float* gapb = ws + 13275104;
  float* svec = ws + 13276544;
  ushort* Wg1 = (ushort*)(ws + 13278000);
  ushort* Wg2 = (ushort*)(ws + 13333296);
  ushort* Wp1 = (ushort*)(ws + 13388592);
  ushort* Wp2 = (ushort*)(ws + 13462320);
  ushort* Wpa = (ushort*)(ws + 13499184);
  ushort* Bfx = (ushort*)(ws + 13517616);
  ushort* Tmw = (ushort*)(ws + 13522992);
  ushort* Bix = (ushort*)(ws + 13532208);
  ushort* Wbk = (ushort*)(ws + 13538352);
  ushort* Wdk = (ushort*)(ws + 13593648);
  float* big  = ws + 13780096;
  float* ximg = big;
  float* spec = big + 13271040;
  ushort* mid = (ushort*)(big + 26818560);
  float* attn = big + 29030400;
  ushort* ycab = (ushort*)spec;
  ushort* xn2 = (ushort*)(big + 30210048);
  ushort* t1  = (ushort*)big;
  float*  reg2= big + 26542080;
  ushort* pgb = (ushort*)reg2;

  k_packw<<<576,256,0,stream>>>(cab_w1, cab_w2, fc1_w, fc2_w, aggr_w, band_w,
                                Wg1, Wg2, Wp1, Wp2, Wpa, Wbk, Bfx, Tmw, Bix, m1, gapb);
  k_ln1<<<2304,256,0,stream>>>(x, ln1_g, ln1_b, ximg, m1);
  k_small<<<1,64,0,stream>>>(m1, gate_w, gate_b, dwc_w1, dwc_b1, dwc_w2, dwc_b2, band_b, gates, dkb, biasb);
  k_packplk<<<1456,256,0,stream>>>(plkw, dkb, Wdk);
  k_fft_fwd<<<1440,512,0,stream>>>(ximg, Bfx, Tmw, spec);
  k_bandmixm<<<dim3(147,Bb),512,0,stream>>>(spec, Wbk, gates);
  k_fft_inv<<<1440,512,0,stream>>>(spec, ximg, biasb, Tmw, Bix);
  k_cab<4, Cc, 192, 6, true,  true ><<<dim3(48,1,Bb),256,0,stream>>>((const ushort*)spec, Wg1, cab_b1, mid, CRr, 2*SPL, nullptr);
  k_cab<4, CRr, 64, 2, false, false><<<dim3(48,3,Bb),256,0,stream>>>(mid, Wg2, cab_b2, ycab, Cc, HWn, gapb);
  k_eca<<<6,256,0,stream>>>(gapb, eca_w, svec);
  k_plkm<<<dim3(32,Bb),384,0,stream>>>(ximg, Wdk, attn);
  k_aggrm<<<1152,512,0,stream>>>(x, attn, ximg, ycab, Wpa, aggr_b, svec, ln2_g, ln2_b, xm, xn2);
  k_fc1<<<1152,256,0,stream>>>(xn2, Wp1, fc1_b, t1);
  k_dwglu<<<dim3(9,HID,Bb),256,0,stream>>>((const bf16*)t1, dw_w, dw_b, (bf16*)pgb);
  k_fc2<<<2304,256,0,stream>>>(pgb, xm, Wp2, fc2_b, (float*)d_out);
}